// Round 1
// baseline (14378.798 us; speedup 1.0000x reference)
//
#include <hip/hip_runtime.h>
#include <cmath>

#define LRELU(x) ((x) > 0.0f ? (x) : 0.01f * (x))

enum { MODE_WRITE = 0, MODE_ADD_AFTER = 1, MODE_ADD_BEFORE = 2 };

// ---------------------------------------------------------------------------
// IMG_GRID synthesis: gbuf[n*32 + c] = sin(r_t * 2^((c/2)/2)),
// t = (c odd) ? (n%256) : (n/256), r_t = (t-128)*pi/256   (double, like numpy)
// ---------------------------------------------------------------------------
__global__ void grid_kernel(float* __restrict__ gbuf) {
    int idx = blockIdx.x * blockDim.x + threadIdx.x;   // 0 .. 65536*32-1
    int n = idx >> 5, c = idx & 31;
    int i = n >> 8, j = n & 255;
    int t = (c & 1) ? j : i;
    double r = (double)(t - 128) * 3.14159265358979323846;
    r = r / 256.0;
    double scale = exp2(0.5 * (double)(c >> 1));
    gbuf[idx] = (float)sin(r * scale);
}

// ---------------------------------------------------------------------------
// Grouped 3x3 conv + leaky relu. One block per output channel, one thread per
// output pixel. pad = 1 (SAME) or 0 (VALID).
// ---------------------------------------------------------------------------
__global__ void conv3x3_kernel(const float* __restrict__ x, const float* __restrict__ w,
                               const float* __restrict__ bias, float* __restrict__ y,
                               int Cin_g, int Cout_g, int Hin, int pad) {
    int oc = blockIdx.x;
    int Hout = pad ? Hin : Hin - 2;
    int p = threadIdx.x;
    if (p >= Hout * Hout) return;
    int oy = p / Hout, ox = p % Hout;
    int g = oc / Cout_g;
    const float* wb = w + (size_t)oc * Cin_g * 9;
    const float* xb = x + (size_t)g * Cin_g * Hin * Hin;
    float acc = bias[oc];
    for (int ic = 0; ic < Cin_g; ++ic) {
        const float* xc = xb + (size_t)ic * Hin * Hin;
        const float* wc = wb + (size_t)ic * 9;
        #pragma unroll
        for (int ky = 0; ky < 3; ++ky) {
            int iy = oy + ky - pad;
            if (iy < 0 || iy >= Hin) continue;
            #pragma unroll
            for (int kx = 0; kx < 3; ++kx) {
                int ix = ox + kx - pad;
                if (ix < 0 || ix >= Hin) continue;
                acc = fmaf(xc[iy * Hin + ix], wc[ky * 3 + kx], acc);
            }
        }
    }
    y[(size_t)oc * Hout * Hout + p] = LRELU(acc);
}

// ---------------------------------------------------------------------------
// c1[o] = b1[o] + sum_k feat[k] * w1[o][32+k]   (one wave per output row)
// ---------------------------------------------------------------------------
__global__ void feat_c1_kernel(const float* __restrict__ feat, const float* __restrict__ w1,
                               const float* __restrict__ b1, float* __restrict__ c1) {
    int o = (blockIdx.x * blockDim.x + threadIdx.x) >> 6;
    int lane = threadIdx.x & 63;
    if (o >= 1024) return;
    const float* wr = w1 + (size_t)o * 2080 + 32;
    float sum = 0.f;
    for (int k = lane; k < 2048; k += 64) sum += feat[k] * wr[k];
    #pragma unroll
    for (int off = 32; off; off >>= 1) sum += __shfl_xor(sum, off);
    if (lane == 0) c1[o] = sum + b1[o];
}

// ---------------------------------------------------------------------------
// Weight-norm row scales: s[r] = g[r] / ||v[r,:]||  (one wave per row)
// ---------------------------------------------------------------------------
__global__ void wn_scale_kernel(const float* __restrict__ v, const float* __restrict__ g,
                                float* __restrict__ s, int K, int R) {
    int r = (blockIdx.x * blockDim.x + threadIdx.x) >> 6;
    int lane = threadIdx.x & 63;
    if (r >= R) return;
    const float* vr = v + (size_t)r * K;
    float sum = 0.f;
    for (int k = lane; k < K; k += 64) { float x = vr[k]; sum = fmaf(x, x, sum); }
    #pragma unroll
    for (int off = 32; off; off >>= 1) sum += __shfl_xor(sum, off);
    if (lane == 0) s[r] = g[r] / sqrtf(sum);
}

// ---------------------------------------------------------------------------
// fp32 GEMM: D[m,n] (epilogue) <= A[M,K](lda) * B[N,K](ldb)^T
// 64x64 tile, BK=16, 256 threads, 4x4 micro-tile, k-major LDS (+4 pad).
// Epilogue: v = acc * (scale?s[n]:1) + (bias?b[n]:0)
//   MODE_WRITE     : D = act(v)
//   MODE_ADD_AFTER : D = D + act(v)        (additive coupling)
//   MODE_ADD_BEFORE: D = act(D + v)        (concat-GEMM second half)
// ---------------------------------------------------------------------------
__global__ __launch_bounds__(256) void gemm64(
    const float* __restrict__ A, int lda,
    const float* __restrict__ B, int ldb,
    float* __restrict__ D, int ldd,
    const float* __restrict__ scale, const float* __restrict__ bias,
    int K, int mode, int act) {
    __shared__ float As[16][68];
    __shared__ float Bs[16][68];
    int tid = threadIdx.x;
    int bm = blockIdx.x, bn = blockIdx.y;
    const float* Ab = A + (size_t)bm * 64 * lda;
    const float* Bb = B + (size_t)bn * 64 * ldb;
    int lrow = tid >> 2;          // 0..63 : tile row
    int lk4 = (tid & 3) * 4;      // 0,4,8,12 : k sub-chunk
    int tm = tid >> 4, tn = tid & 15;
    float acc[4][4] = {};
    for (int k0 = 0; k0 < K; k0 += 16) {
        float4 av = *reinterpret_cast<const float4*>(Ab + (size_t)lrow * lda + k0 + lk4);
        float4 bv = *reinterpret_cast<const float4*>(Bb + (size_t)lrow * ldb + k0 + lk4);
        __syncthreads();
        As[lk4 + 0][lrow] = av.x; As[lk4 + 1][lrow] = av.y;
        As[lk4 + 2][lrow] = av.z; As[lk4 + 3][lrow] = av.w;
        Bs[lk4 + 0][lrow] = bv.x; Bs[lk4 + 1][lrow] = bv.y;
        Bs[lk4 + 2][lrow] = bv.z; Bs[lk4 + 3][lrow] = bv.w;
        __syncthreads();
        #pragma unroll
        for (int k = 0; k < 16; ++k) {
            float4 a4 = *reinterpret_cast<const float4*>(&As[k][tm * 4]);
            float4 b4 = *reinterpret_cast<const float4*>(&Bs[k][tn * 4]);
            float ar[4] = {a4.x, a4.y, a4.z, a4.w};
            float br[4] = {b4.x, b4.y, b4.z, b4.w};
            #pragma unroll
            for (int i = 0; i < 4; ++i)
                #pragma unroll
                for (int j = 0; j < 4; ++j)
                    acc[i][j] = fmaf(ar[i], br[j], acc[i][j]);
        }
    }
    #pragma unroll
    for (int i = 0; i < 4; ++i) {
        int m = bm * 64 + tm * 4 + i;
        #pragma unroll
        for (int j = 0; j < 4; ++j) {
            int n = bn * 64 + tn * 4 + j;
            float v = acc[i][j];
            if (scale) v *= scale[n];
            if (bias)  v += bias[n];
            float* dp = D + (size_t)m * ldd + n;
            if (mode == MODE_ADD_BEFORE) v += *dp;
            if (act) v = LRELU(v);
            if (mode == MODE_ADD_AFTER) v += *dp;
            *dp = v;
        }
    }
}

// ---------------------------------------------------------------------------
// Final layer: out[c,n0+m] = 1.1*sigmoid(h[m]·w3[c] + b3[c]) - 0.05
// one wave per row m.
// ---------------------------------------------------------------------------
__global__ void rgb_kernel(const float* __restrict__ H, const float* __restrict__ w3,
                           const float* __restrict__ b3, float* __restrict__ out,
                           int n0, int Nc) {
    int m = (blockIdx.x * blockDim.x + threadIdx.x) >> 6;
    int lane = threadIdx.x & 63;
    if (m >= Nc) return;
    const float* h = H + (size_t)m * 512;
    float s0 = 0.f, s1 = 0.f, s2 = 0.f;
    for (int k = lane; k < 512; k += 64) {
        float hv = h[k];
        s0 = fmaf(hv, w3[k], s0);
        s1 = fmaf(hv, w3[512 + k], s1);
        s2 = fmaf(hv, w3[1024 + k], s2);
    }
    #pragma unroll
    for (int off = 32; off; off >>= 1) {
        s0 += __shfl_xor(s0, off);
        s1 += __shfl_xor(s1, off);
        s2 += __shfl_xor(s2, off);
    }
    if (lane == 0) {
        float v[3] = {s0 + b3[0], s1 + b3[1], s2 + b3[2]};
        #pragma unroll
        for (int c = 0; c < 3; ++c) {
            float sg = 1.0f / (1.0f + expf(-v[c]));
            out[(size_t)c * 65536 + n0 + m] = 1.1f * sg - 0.05f;
        }
    }
}

extern "C" void kernel_launch(void* const* d_in, const int* in_sizes, int n_in,
                              void* d_out, int out_size, void* d_ws, size_t ws_size,
                              hipStream_t stream) {
    const float* feature = (const float*)d_in[0];
    const float* cw1 = (const float*)d_in[1];  const float* cb1 = (const float*)d_in[2];
    const float* cw2 = (const float*)d_in[3];  const float* cb2 = (const float*)d_in[4];
    const float* cw3 = (const float*)d_in[5];  const float* cb3 = (const float*)d_in[6];
    const float* cw4 = (const float*)d_in[7];  const float* cb4 = (const float*)d_in[8];
    const float* cw5 = (const float*)d_in[9];  const float* cb5 = (const float*)d_in[10];
    const float* w1  = (const float*)d_in[11]; const float* b1  = (const float*)d_in[12];
    const float* m1_vf = (const float*)d_in[13]; const float* m1_gf = (const float*)d_in[14];
    const float* m1_bf = (const float*)d_in[15];
    const float* m1_vg = (const float*)d_in[16]; const float* m1_gg = (const float*)d_in[17];
    const float* m1_bg = (const float*)d_in[18];
    const float* w2  = (const float*)d_in[19]; const float* b2  = (const float*)d_in[20];
    const float* m2_vf = (const float*)d_in[21]; const float* m2_gf = (const float*)d_in[22];
    const float* m2_bf = (const float*)d_in[23];
    const float* m2_vg = (const float*)d_in[24]; const float* m2_gg = (const float*)d_in[25];
    const float* m2_bg = (const float*)d_in[26];
    const float* w3  = (const float*)d_in[27]; const float* b3  = (const float*)d_in[28];
    float* out = (float*)d_out;

    float* ws = (float*)d_ws;
    size_t off = 0;
    float* gridbuf = ws + off; off += (size_t)65536 * 32;   // 2,097,152
    float* cbA     = ws + off; off += 768 * 64;             // conv ping
    float* cbB     = ws + off; off += 768 * 64;             // conv pong
    float* featbuf = ws + off; off += 2048;
    float* c1      = ws + off; off += 1024;
    float* s1f     = ws + off; off += 8 * 512;
    float* s1g     = ws + off; off += 8 * 512;
    float* s2f     = ws + off; off += 8 * 256;
    float* s2g     = ws + off; off += 8 * 256;
    size_t fixedF  = off;

    int CH = 16384;  // chunk of positions; shrink if workspace is small
    while (CH > 64 && (fixedF + (size_t)CH * 1536) * sizeof(float) > ws_size) CH >>= 1;
    float* mid = ws + fixedF;                 // [CH,1024]
    float* h2b = mid + (size_t)CH * 1024;     // [CH,512]

    // ---- constants: IMG_GRID, wn scales ----
    grid_kernel<<<(65536 * 32) / 256, 256, 0, stream>>>(gridbuf);
    wn_scale_kernel<<<(8 * 512) / 4, 256, 0, stream>>>(m1_vf, m1_gf, s1f, 512, 8 * 512);
    wn_scale_kernel<<<(8 * 512) / 4, 256, 0, stream>>>(m1_vg, m1_gg, s1g, 512, 8 * 512);
    wn_scale_kernel<<<(8 * 256) / 4, 256, 0, stream>>>(m2_vf, m2_gf, s2f, 256, 8 * 256);
    wn_scale_kernel<<<(8 * 256) / 4, 256, 0, stream>>>(m2_vg, m2_gg, s2g, 256, 8 * 256);

    // ---- conv trunk ----
    conv3x3_kernel<<<768, 64, 0, stream>>>(feature, cw1, cb1, cbA, 448, 192, 8, 1);
    conv3x3_kernel<<<768, 64, 0, stream>>>(cbA, cw2, cb2, cbB, 256, 256, 8, 1);
    conv3x3_kernel<<<768, 64, 0, stream>>>(cbB, cw3, cb3, cbA, 384, 384, 8, 1);
    conv3x3_kernel<<<768, 64, 0, stream>>>(cbA, cw4, cb4, cbB, 256, 256, 8, 0);   // ->6x6
    conv3x3_kernel<<<128, 64, 0, stream>>>(cbB, cw5, cb5, featbuf, 768, 128, 6, 0); // ->4x4 (feat 2048)

    // ---- c1 = feat @ w1[:,32:].T + b1 ----
    feat_c1_kernel<<<1024 / 4, 256, 0, stream>>>(featbuf, w1, b1, c1);

    // ---- per-position MLP in chunks ----
    for (int n0 = 0; n0 < 65536; n0 += CH) {
        const float* gchunk = gridbuf + (size_t)n0 * 32;
        // mid = lrelu(grid @ w1[:,:32].T + c1)
        gemm64<<<dim3(CH / 64, 1024 / 64), 256, 0, stream>>>(
            gchunk, 32, w1, 2080, mid, 1024, nullptr, c1, 32, MODE_WRITE, 1);
        // coupling stack 1 (512-dim halves), in place
        for (int t = 0; t < 8; ++t) {
            gemm64<<<dim3(CH / 64, 8), 256, 0, stream>>>(
                mid + 512, 1024, m1_vf + (size_t)t * 512 * 512, 512, mid, 1024,
                s1f + t * 512, m1_bf + t * 512, 512, MODE_ADD_AFTER, 1);
            gemm64<<<dim3(CH / 64, 8), 256, 0, stream>>>(
                mid, 1024, m1_vg + (size_t)t * 512 * 512, 512, mid + 512, 1024,
                s1g + t * 512, m1_bg + t * 512, 512, MODE_ADD_AFTER, 1);
        }
        // h2 = lrelu(grid @ w2[:,:32].T + mid @ w2[:,32:].T + b2)
        gemm64<<<dim3(CH / 64, 8), 256, 0, stream>>>(
            gchunk, 32, w2, 1056, h2b, 512, nullptr, nullptr, 32, MODE_WRITE, 0);
        gemm64<<<dim3(CH / 64, 8), 256, 0, stream>>>(
            mid, 1024, w2 + 32, 1056, h2b, 512, nullptr, b2, 1024, MODE_ADD_BEFORE, 1);
        // coupling stack 2 (256-dim halves), in place
        for (int t = 0; t < 8; ++t) {
            gemm64<<<dim3(CH / 64, 4), 256, 0, stream>>>(
                h2b + 256, 512, m2_vf + (size_t)t * 256 * 256, 256, h2b, 512,
                s2f + t * 256, m2_bf + t * 256, 256, MODE_ADD_AFTER, 1);
            gemm64<<<dim3(CH / 64, 4), 256, 0, stream>>>(
                h2b, 512, m2_vg + (size_t)t * 256 * 256, 256, h2b + 256, 512,
                s2g + t * 256, m2_bg + t * 256, 256, MODE_ADD_AFTER, 1);
        }
        // rgb + transpose + affine
        rgb_kernel<<<CH / 4, 256, 0, stream>>>(h2b, w3, b3, out, n0, CH);
    }
}

// Round 2
// 5644.700 us; speedup vs baseline: 2.5473x; 2.5473x over previous
//
#include <hip/hip_runtime.h>
#include <cmath>

#define LRELU(x) ((x) > 0.0f ? (x) : 0.01f * (x))

enum { MODE_WRITE = 0, MODE_ADD_AFTER = 1, MODE_ADD_BEFORE = 2 };

typedef __attribute__((ext_vector_type(8))) short short8;
typedef __attribute__((ext_vector_type(4))) float f32x4;

__device__ __forceinline__ unsigned short f2bf(float f) {
    unsigned u = __float_as_uint(f);
    unsigned r = (u + 0x7fff + ((u >> 16) & 1)) >> 16;   // RNE
    return (unsigned short)r;
}

__device__ __forceinline__ void load_lds16(const void* g, void* l) {
    __builtin_amdgcn_global_load_lds(
        (const __attribute__((address_space(1))) unsigned*)g,
        (__attribute__((address_space(3))) unsigned*)l, 16, 0, 0);
}

// ---------------------------------------------------------------------------
// IMG_GRID synthesis (double precision to match numpy)
// ---------------------------------------------------------------------------
__global__ void grid_kernel(float* __restrict__ gbuf) {
    int idx = blockIdx.x * blockDim.x + threadIdx.x;   // 0 .. 65536*32-1
    int n = idx >> 5, c = idx & 31;
    int i = n >> 8, j = n & 255;
    int t = (c & 1) ? j : i;
    double r = (double)(t - 128) * 3.14159265358979323846 / 256.0;
    double scale = exp2(0.5 * (double)(c >> 1));
    gbuf[idx] = (float)sin(r * scale);
}

// ---------------------------------------------------------------------------
// Grouped 3x3 conv + lrelu. Block = one out channel, 256 thr = 64 px x 4
// ic-chunks, LDS reduce. Fixes round-0's 1-wave latency-bound version.
// ---------------------------------------------------------------------------
__global__ __launch_bounds__(256) void conv3x3_kernel(
    const float* __restrict__ x, const float* __restrict__ w,
    const float* __restrict__ bias, float* __restrict__ y,
    int Cin_g, int Cout_g, int Hin, int pad) {
    __shared__ float red[256];
    int oc = blockIdx.x;
    int Hout = pad ? Hin : Hin - 2;
    int t = threadIdx.x;
    int p = t & 63, ch = t >> 6;
    int oy = p / Hout, ox = p % Hout;
    int g = oc / Cout_g;
    const float* wb = w + (size_t)oc * Cin_g * 9;
    const float* xb = x + (size_t)g * Cin_g * Hin * Hin;
    bool valid = (p < Hout * Hout);
    int S = (Cin_g + 3) >> 2;
    int ic0 = ch * S, ic1 = min(Cin_g, ic0 + S);
    float acc = 0.f;
    if (valid) {
        for (int ic = ic0; ic < ic1; ++ic) {
            const float* xc = xb + (size_t)ic * Hin * Hin;
            const float* wc = wb + (size_t)ic * 9;
            #pragma unroll
            for (int ky = 0; ky < 3; ++ky) {
                int iy = oy + ky - pad;
                if (iy < 0 || iy >= Hin) continue;
                #pragma unroll
                for (int kx = 0; kx < 3; ++kx) {
                    int ix = ox + kx - pad;
                    if (ix < 0 || ix >= Hin) continue;
                    acc = fmaf(xc[iy * Hin + ix], wc[ky * 3 + kx], acc);
                }
            }
        }
    }
    red[t] = acc;
    __syncthreads();
    if (t < 64 && valid) {
        float s = red[t] + red[t + 64] + red[t + 128] + red[t + 192] + bias[oc];
        y[(size_t)oc * Hout * Hout + p] = LRELU(s);
    }
}

// ---------------------------------------------------------------------------
// c1[o] = b1[o] + feat . w1[o][32:]
// ---------------------------------------------------------------------------
__global__ void feat_c1_kernel(const float* __restrict__ feat, const float* __restrict__ w1,
                               const float* __restrict__ b1, float* __restrict__ c1) {
    int o = (blockIdx.x * blockDim.x + threadIdx.x) >> 6;
    int lane = threadIdx.x & 63;
    if (o >= 1024) return;
    const float* wr = w1 + (size_t)o * 2080 + 32;
    float sum = 0.f;
    for (int k = lane; k < 2048; k += 64) sum += feat[k] * wr[k];
    #pragma unroll
    for (int off = 32; off; off >>= 1) sum += __shfl_xor(sum, off);
    if (lane == 0) c1[o] = sum + b1[o];
}

__global__ void wn_scale_kernel(const float* __restrict__ v, const float* __restrict__ g,
                                float* __restrict__ s, int K, int R) {
    int r = (blockIdx.x * blockDim.x + threadIdx.x) >> 6;
    int lane = threadIdx.x & 63;
    if (r >= R) return;
    const float* vr = v + (size_t)r * K;
    float sum = 0.f;
    for (int k = lane; k < K; k += 64) { float x = vr[k]; sum = fmaf(x, x, sum); }
    #pragma unroll
    for (int off = 32; off; off >>= 1) sum += __shfl_xor(sum, off);
    if (lane == 0) s[r] = g[r] / sqrtf(sum);
}

// ---------------------------------------------------------------------------
// float -> bf16 weight conversion
// ---------------------------------------------------------------------------
__global__ void cvt_bf16_kernel(const float* __restrict__ src, unsigned short* __restrict__ dst, int n) {
    int i = blockIdx.x * 256 + threadIdx.x;
    if (i < n) dst[i] = f2bf(src[i]);
}
// w2[:, 32:] (512 x 1024 out of ld 1056)
__global__ void cvt_w2_kernel(const float* __restrict__ w2, unsigned short* __restrict__ dst) {
    int i = blockIdx.x * 256 + threadIdx.x;   // 512*1024
    int r = i >> 10, c = i & 1023;
    dst[i] = f2bf(w2[(size_t)r * 1056 + 32 + c]);
}

// ---------------------------------------------------------------------------
// fp32 GEMM (kept for K=32 grid matmuls): D = A[M,K] * B[N,K]^T
// ---------------------------------------------------------------------------
__global__ __launch_bounds__(256) void gemm64(
    const float* __restrict__ A, int lda,
    const float* __restrict__ B, int ldb,
    float* __restrict__ D, unsigned short* __restrict__ Dbf, int ldd,
    const float* __restrict__ scale, const float* __restrict__ bias,
    int K, int mode, int act) {
    __shared__ float As[16][68];
    __shared__ float Bs[16][68];
    int tid = threadIdx.x;
    int bm = blockIdx.x, bn = blockIdx.y;
    const float* Ab = A + (size_t)bm * 64 * lda;
    const float* Bb = B + (size_t)bn * 64 * ldb;
    int lrow = tid >> 2;
    int lk4 = (tid & 3) * 4;
    int tm = tid >> 4, tn = tid & 15;
    float acc[4][4] = {};
    for (int k0 = 0; k0 < K; k0 += 16) {
        float4 av = *reinterpret_cast<const float4*>(Ab + (size_t)lrow * lda + k0 + lk4);
        float4 bv = *reinterpret_cast<const float4*>(Bb + (size_t)lrow * ldb + k0 + lk4);
        __syncthreads();
        As[lk4 + 0][lrow] = av.x; As[lk4 + 1][lrow] = av.y;
        As[lk4 + 2][lrow] = av.z; As[lk4 + 3][lrow] = av.w;
        Bs[lk4 + 0][lrow] = bv.x; Bs[lk4 + 1][lrow] = bv.y;
        Bs[lk4 + 2][lrow] = bv.z; Bs[lk4 + 3][lrow] = bv.w;
        __syncthreads();
        #pragma unroll
        for (int k = 0; k < 16; ++k) {
            float4 a4 = *reinterpret_cast<const float4*>(&As[k][tm * 4]);
            float4 b4 = *reinterpret_cast<const float4*>(&Bs[k][tn * 4]);
            float ar[4] = {a4.x, a4.y, a4.z, a4.w};
            float br[4] = {b4.x, b4.y, b4.z, b4.w};
            #pragma unroll
            for (int i = 0; i < 4; ++i)
                #pragma unroll
                for (int j = 0; j < 4; ++j)
                    acc[i][j] = fmaf(ar[i], br[j], acc[i][j]);
        }
    }
    #pragma unroll
    for (int i = 0; i < 4; ++i) {
        int m = bm * 64 + tm * 4 + i;
        #pragma unroll
        for (int j = 0; j < 4; ++j) {
            int n = bn * 64 + tn * 4 + j;
            float v = acc[i][j];
            if (scale) v *= scale[n];
            if (bias)  v += bias[n];
            float* dp = D + (size_t)m * ldd + n;
            if (mode == MODE_ADD_BEFORE) v += *dp;
            if (act) v = LRELU(v);
            if (mode == MODE_ADD_AFTER) v += *dp;
            *dp = v;
            if (Dbf) Dbf[(size_t)m * ldd + n] = f2bf(v);
        }
    }
}

// ---------------------------------------------------------------------------
// bf16 MFMA GEMM (m97 structure): D[m,n] <= A[M,K]bf16 * B[N,K]bf16^T
// 128x128 tile, BK=64, 256 thr (4 waves, 2x2 of 64x64), 4x4 of 16x16x32 MFMA.
// A,B staged via global_load_lds width=16. Epilogue identical to gemm64,
// optionally writing a bf16 shadow of D.
// ---------------------------------------------------------------------------
__global__ __launch_bounds__(256) void gemm_mfma(
    const unsigned short* __restrict__ A, int lda,
    const unsigned short* __restrict__ B, int ldb,
    float* __restrict__ D, unsigned short* __restrict__ Dbf, int ldd,
    const float* __restrict__ scale, const float* __restrict__ bias,
    int K, int mode, int act) {
    __shared__ unsigned short As[128 * 64];   // row-major, 64 bf16 per row
    __shared__ unsigned short Bs[128 * 64];
    int tid = threadIdx.x;
    int wid = tid >> 6, lane = tid & 63;
    int wy = wid & 1, wx = wid >> 1;
    int frow = lane & 15, fquad = lane >> 4;
    int bm = blockIdx.x, bn = blockIdx.y;
    const unsigned short* Ab = A + (size_t)bm * 128 * lda;
    const unsigned short* Bb = B + (size_t)bn * 128 * ldb;

    f32x4 acc[4][4] = {};

    for (int k0 = 0; k0 < K; k0 += 64) {
        __syncthreads();
        #pragma unroll
        for (int q = 0; q < 4; ++q) {
            int c = (wid * 4 + q) * 64 + lane;      // 0..1023 chunks of 16B
            int row = c >> 3, col8 = (c & 7) * 8;
            // wave-uniform LDS base; HW scatters lane i at +16*i
            load_lds16(Ab + (size_t)row * lda + k0 + col8, (void*)(As + (size_t)(wid * 4 + q) * 512));
        }
        #pragma unroll
        for (int q = 0; q < 4; ++q) {
            int c = (wid * 4 + q) * 64 + lane;
            int row = c >> 3, col8 = (c & 7) * 8;
            load_lds16(Bb + (size_t)row * ldb + k0 + col8, (void*)(Bs + (size_t)(wid * 4 + q) * 512));
        }
        __syncthreads();
        #pragma unroll
        for (int ks = 0; ks < 64; ks += 32) {
            short8 af[4], bfr[4];
            #pragma unroll
            for (int i = 0; i < 4; ++i)
                af[i] = *(const short8*)(As + (size_t)(wy * 64 + i * 16 + frow) * 64 + ks + fquad * 8);
            #pragma unroll
            for (int j = 0; j < 4; ++j)
                bfr[j] = *(const short8*)(Bs + (size_t)(wx * 64 + j * 16 + frow) * 64 + ks + fquad * 8);
            #pragma unroll
            for (int i = 0; i < 4; ++i)
                #pragma unroll
                for (int j = 0; j < 4; ++j)
                    acc[i][j] = __builtin_amdgcn_mfma_f32_16x16x32_bf16(af[i], bfr[j], acc[i][j], 0, 0, 0);
        }
    }

    #pragma unroll
    for (int i = 0; i < 4; ++i) {
        #pragma unroll
        for (int j = 0; j < 4; ++j) {
            int n = bn * 128 + wx * 64 + j * 16 + frow;
            float sc = scale ? scale[n] : 1.0f;
            float bi = bias ? bias[n] : 0.0f;
            #pragma unroll
            for (int r = 0; r < 4; ++r) {
                int m = bm * 128 + wy * 64 + i * 16 + fquad * 4 + r;
                float v = acc[i][j][r] * sc + bi;
                float* dp = D + (size_t)m * ldd + n;
                if (mode == MODE_ADD_BEFORE) v += *dp;
                if (act) v = LRELU(v);
                if (mode == MODE_ADD_AFTER) v += *dp;
                *dp = v;
                if (Dbf) Dbf[(size_t)m * ldd + n] = f2bf(v);
            }
        }
    }
}

// ---------------------------------------------------------------------------
// Final layer: out[c, n0+m] = 1.1*sigmoid(h[m].w3[c] + b3[c]) - 0.05
// ---------------------------------------------------------------------------
__global__ void rgb_kernel(const float* __restrict__ H, const float* __restrict__ w3,
                           const float* __restrict__ b3, float* __restrict__ out,
                           int n0, int Nc) {
    int m = (blockIdx.x * blockDim.x + threadIdx.x) >> 6;
    int lane = threadIdx.x & 63;
    if (m >= Nc) return;
    const float* h = H + (size_t)m * 512;
    float s0 = 0.f, s1 = 0.f, s2 = 0.f;
    for (int k = lane; k < 512; k += 64) {
        float hv = h[k];
        s0 = fmaf(hv, w3[k], s0);
        s1 = fmaf(hv, w3[512 + k], s1);
        s2 = fmaf(hv, w3[1024 + k], s2);
    }
    #pragma unroll
    for (int off = 32; off; off >>= 1) {
        s0 += __shfl_xor(s0, off);
        s1 += __shfl_xor(s1, off);
        s2 += __shfl_xor(s2, off);
    }
    if (lane == 0) {
        float v[3] = {s0 + b3[0], s1 + b3[1], s2 + b3[2]};
        #pragma unroll
        for (int c = 0; c < 3; ++c) {
            float sg = 1.0f / (1.0f + expf(-v[c]));
            out[(size_t)c * 65536 + n0 + m] = 1.1f * sg - 0.05f;
        }
    }
}

extern "C" void kernel_launch(void* const* d_in, const int* in_sizes, int n_in,
                              void* d_out, int out_size, void* d_ws, size_t ws_size,
                              hipStream_t stream) {
    const float* feature = (const float*)d_in[0];
    const float* cw1 = (const float*)d_in[1];  const float* cb1 = (const float*)d_in[2];
    const float* cw2 = (const float*)d_in[3];  const float* cb2 = (const float*)d_in[4];
    const float* cw3 = (const float*)d_in[5];  const float* cb3 = (const float*)d_in[6];
    const float* cw4 = (const float*)d_in[7];  const float* cb4 = (const float*)d_in[8];
    const float* cw5 = (const float*)d_in[9];  const float* cb5 = (const float*)d_in[10];
    const float* w1  = (const float*)d_in[11]; const float* b1  = (const float*)d_in[12];
    const float* m1_vf = (const float*)d_in[13]; const float* m1_gf = (const float*)d_in[14];
    const float* m1_bf = (const float*)d_in[15];
    const float* m1_vg = (const float*)d_in[16]; const float* m1_gg = (const float*)d_in[17];
    const float* m1_bg = (const float*)d_in[18];
    const float* w2  = (const float*)d_in[19]; const float* b2  = (const float*)d_in[20];
    const float* m2_vf = (const float*)d_in[21]; const float* m2_gf = (const float*)d_in[22];
    const float* m2_bf = (const float*)d_in[23];
    const float* m2_vg = (const float*)d_in[24]; const float* m2_gg = (const float*)d_in[25];
    const float* m2_bg = (const float*)d_in[26];
    const float* w3  = (const float*)d_in[27]; const float* b3  = (const float*)d_in[28];
    float* out = (float*)d_out;

    float* ws = (float*)d_ws;
    size_t off = 0;
    float* gridbuf = ws + off; off += (size_t)65536 * 32;
    float* cbA     = ws + off; off += 768 * 64;
    float* cbB     = ws + off; off += 768 * 64;
    float* featbuf = ws + off; off += 2048;
    float* c1      = ws + off; off += 1024;
    float* s1f     = ws + off; off += 8 * 512;
    float* s1g     = ws + off; off += 8 * 512;
    float* s2f     = ws + off; off += 8 * 256;
    float* s2g     = ws + off; off += 8 * 256;
    // bf16 weight copies (ushort; sizes given in float units = elems/2)
    unsigned short* m1f_bf = (unsigned short*)(ws + off); off += (size_t)8 * 512 * 512 / 2;
    unsigned short* m1g_bf = (unsigned short*)(ws + off); off += (size_t)8 * 512 * 512 / 2;
    unsigned short* m2f_bf = (unsigned short*)(ws + off); off += (size_t)8 * 256 * 256 / 2;
    unsigned short* m2g_bf = (unsigned short*)(ws + off); off += (size_t)8 * 256 * 256 / 2;
    unsigned short* w2m_bf = (unsigned short*)(ws + off); off += (size_t)512 * 1024 / 2;
    size_t fixedF = off;

    // per-position: mid f32 (1024) + h2 f32 (512) + mid bf16 (512f) + h2 bf16 (256f)
    int CH = 65536;
    while (CH > 128 && (fixedF + (size_t)CH * 2304) * sizeof(float) > ws_size) CH >>= 1;
    float* mid = ws + fixedF;                                  // [CH,1024] f32
    float* h2b = mid + (size_t)CH * 1024;                      // [CH,512]  f32
    unsigned short* mid_bf = (unsigned short*)(h2b + (size_t)CH * 512);   // [CH,1024] bf16
    unsigned short* h2_bf  = mid_bf + (size_t)CH * 1024;                  // [CH,512]  bf16

    // ---- constants: IMG_GRID, wn scales, bf16 weights ----
    grid_kernel<<<(65536 * 32) / 256, 256, 0, stream>>>(gridbuf);
    wn_scale_kernel<<<(8 * 512) / 4, 256, 0, stream>>>(m1_vf, m1_gf, s1f, 512, 8 * 512);
    wn_scale_kernel<<<(8 * 512) / 4, 256, 0, stream>>>(m1_vg, m1_gg, s1g, 512, 8 * 512);
    wn_scale_kernel<<<(8 * 256) / 4, 256, 0, stream>>>(m2_vf, m2_gf, s2f, 256, 8 * 256);
    wn_scale_kernel<<<(8 * 256) / 4, 256, 0, stream>>>(m2_vg, m2_gg, s2g, 256, 8 * 256);
    {
        int n1 = 8 * 512 * 512, n2 = 8 * 256 * 256, n3 = 512 * 1024;
        cvt_bf16_kernel<<<(n1 + 255) / 256, 256, 0, stream>>>(m1_vf, m1f_bf, n1);
        cvt_bf16_kernel<<<(n1 + 255) / 256, 256, 0, stream>>>(m1_vg, m1g_bf, n1);
        cvt_bf16_kernel<<<(n2 + 255) / 256, 256, 0, stream>>>(m2_vf, m2f_bf, n2);
        cvt_bf16_kernel<<<(n2 + 255) / 256, 256, 0, stream>>>(m2_vg, m2g_bf, n2);
        cvt_w2_kernel<<<(n3 + 255) / 256, 256, 0, stream>>>(w2, w2m_bf);
    }

    // ---- conv trunk ----
    conv3x3_kernel<<<768, 256, 0, stream>>>(feature, cw1, cb1, cbA, 448, 192, 8, 1);
    conv3x3_kernel<<<768, 256, 0, stream>>>(cbA, cw2, cb2, cbB, 256, 256, 8, 1);
    conv3x3_kernel<<<768, 256, 0, stream>>>(cbB, cw3, cb3, cbA, 384, 384, 8, 1);
    conv3x3_kernel<<<768, 256, 0, stream>>>(cbA, cw4, cb4, cbB, 256, 256, 8, 0);     // ->6x6
    conv3x3_kernel<<<128, 256, 0, stream>>>(cbB, cw5, cb5, featbuf, 768, 128, 6, 0); // ->4x4

    // ---- c1 = feat @ w1[:,32:].T + b1 ----
    feat_c1_kernel<<<1024 / 4, 256, 0, stream>>>(featbuf, w1, b1, c1);

    // ---- per-position MLP in chunks ----
    for (int n0 = 0; n0 < 65536; n0 += CH) {
        const float* gchunk = gridbuf + (size_t)n0 * 32;
        // mid = lrelu(grid @ w1[:,:32].T + c1), fp32 path + bf16 shadow
        gemm64<<<dim3(CH / 64, 1024 / 64), 256, 0, stream>>>(
            gchunk, 32, w1, 2080, mid, mid_bf, 1024, nullptr, c1, 32, MODE_WRITE, 1);
        // coupling stack 1 (512-dim halves), in place, MFMA
        for (int t = 0; t < 8; ++t) {
            gemm_mfma<<<dim3(CH / 128, 4), 256, 0, stream>>>(
                mid_bf + 512, 1024, m1f_bf + (size_t)t * 512 * 512, 512,
                mid, mid_bf, 1024, s1f + t * 512, m1_bf + t * 512, 512, MODE_ADD_AFTER, 1);
            gemm_mfma<<<dim3(CH / 128, 4), 256, 0, stream>>>(
                mid_bf, 1024, m1g_bf + (size_t)t * 512 * 512, 512,
                mid + 512, mid_bf + 512, 1024, s1g + t * 512, m1_bg + t * 512, 512, MODE_ADD_AFTER, 1);
        }
        // h2 = lrelu(grid @ w2[:,:32].T + mid @ w2[:,32:].T + b2)
        gemm64<<<dim3(CH / 64, 8), 256, 0, stream>>>(
            gchunk, 32, w2, 1056, h2b, nullptr, 512, nullptr, nullptr, 32, MODE_WRITE, 0);
        gemm_mfma<<<dim3(CH / 128, 4), 256, 0, stream>>>(
            mid_bf, 1024, w2m_bf, 1024, h2b, h2_bf, 512, nullptr, b2, 1024, MODE_ADD_BEFORE, 1);
        // coupling stack 2 (256-dim halves), in place, MFMA
        for (int t = 0; t < 8; ++t) {
            gemm_mfma<<<dim3(CH / 128, 2), 256, 0, stream>>>(
                h2_bf + 256, 512, m2f_bf + (size_t)t * 256 * 256, 256,
                h2b, h2_bf, 512, s2f + t * 256, m2_bf + t * 256, 256, MODE_ADD_AFTER, 1);
            gemm_mfma<<<dim3(CH / 128, 2), 256, 0, stream>>>(
                h2_bf, 512, m2g_bf + (size_t)t * 256 * 256, 256,
                h2b + 256, h2_bf + 256, 512, s2g + t * 256, m2_bg + t * 256, 256, MODE_ADD_AFTER, 1);
        }
        // rgb + transpose + affine
        rgb_kernel<<<CH / 4, 256, 0, stream>>>(h2b, w3, b3, out, n0, CH);
    }
}

// Round 3
// 4826.668 us; speedup vs baseline: 2.9790x; 1.1695x over previous
//
#include <hip/hip_runtime.h>
#include <cmath>

#define LRELU(x) ((x) > 0.0f ? (x) : 0.01f * (x))

enum { MODE_WRITE = 0, MODE_ADD_AFTER = 1, MODE_ADD_BEFORE = 2 };

typedef __attribute__((ext_vector_type(8))) short short8;
typedef __attribute__((ext_vector_type(4))) float f32x4;

__device__ __forceinline__ unsigned short f2bf(float f) {
    unsigned u = __float_as_uint(f);
    unsigned r = (u + 0x7fff + ((u >> 16) & 1)) >> 16;   // RNE
    return (unsigned short)r;
}
__device__ __forceinline__ float bf2f(unsigned short h) {
    return __uint_as_float((unsigned)h << 16);
}
// split fp32 into hi+lo bf16 pair (hi is the MFMA operand, hi+lo ~ fp24)
__device__ __forceinline__ void split_write(float x, unsigned short* hi, unsigned short* lo) {
    unsigned short h = f2bf(x);
    *hi = h;
    *lo = f2bf(x - bf2f(h));
}

__device__ __forceinline__ void load_lds16(const void* g, void* l) {
    __builtin_amdgcn_global_load_lds(
        (const __attribute__((address_space(1))) unsigned*)g,
        (__attribute__((address_space(3))) unsigned*)l, 16, 0, 0);
}

// ---------------------------------------------------------------------------
// sgrid[t][c] = sin(r_t * 2^((c/2)/2)), r_t=(t-128)*pi/256  (256 x 32, fp64 math)
// ---------------------------------------------------------------------------
__global__ void sgrid_kernel(float* __restrict__ sg) {
    int idx = blockIdx.x * blockDim.x + threadIdx.x;   // 0..8191
    if (idx >= 256 * 32) return;
    int t = idx >> 5, c = idx & 31;
    double r = (double)(t - 128) * 3.14159265358979323846 / 256.0;
    double scale = exp2(0.5 * (double)(c >> 1));
    sg[idx] = (float)sin(r * scale);
}

// ---------------------------------------------------------------------------
// Conv partial sums: wave per (oc, 16-ic chunk), lane = pixel, atomicAdd.
// ---------------------------------------------------------------------------
__global__ void conv_partial(const float* __restrict__ x, const float* __restrict__ w,
                             float* __restrict__ y,
                             int Cin_g, int Cout_g, int Hin, int pad) {
    int oc = blockIdx.x, ch = blockIdx.y;
    int Hout = pad ? Hin : Hin - 2;
    int lane = threadIdx.x;
    if (lane >= Hout * Hout) return;
    int oy = lane / Hout, ox = lane % Hout;
    int g = oc / Cout_g;
    const float* xb = x + (size_t)g * Cin_g * Hin * Hin;
    const float* wb = w + (size_t)oc * Cin_g * 9;
    int ic0 = ch * 16, ic1 = min(Cin_g, ic0 + 16);
    float acc = 0.f;
    for (int ic = ic0; ic < ic1; ++ic) {
        const float* xc = xb + (size_t)ic * Hin * Hin;
        const float* wc = wb + (size_t)ic * 9;
        #pragma unroll
        for (int ky = 0; ky < 3; ++ky) {
            int iy = oy + ky - pad;
            if (iy < 0 || iy >= Hin) continue;
            #pragma unroll
            for (int kx = 0; kx < 3; ++kx) {
                int ix = ox + kx - pad;
                if (ix < 0 || ix >= Hin) continue;
                acc = fmaf(xc[iy * Hin + ix], wc[ky * 3 + kx], acc);
            }
        }
    }
    atomicAdd(&y[(size_t)oc * Hout * Hout + lane], acc);
}

__global__ void conv_finalize(float* __restrict__ y, const float* __restrict__ bias, int HH, int n) {
    int i = blockIdx.x * 256 + threadIdx.x;
    if (i >= n) return;
    float v = y[i] + bias[i / HH];
    y[i] = LRELU(v);
}

// ---------------------------------------------------------------------------
// c1[o] = b1[o] + feat . w1[o][32:]
// ---------------------------------------------------------------------------
__global__ void feat_c1_kernel(const float* __restrict__ feat, const float* __restrict__ w1,
                               const float* __restrict__ b1, float* __restrict__ c1) {
    int o = (blockIdx.x * blockDim.x + threadIdx.x) >> 6;
    int lane = threadIdx.x & 63;
    if (o >= 1024) return;
    const float* wr = w1 + (size_t)o * 2080 + 32;
    float sum = 0.f;
    for (int k = lane; k < 2048; k += 64) sum += feat[k] * wr[k];
    #pragma unroll
    for (int off = 32; off; off >>= 1) sum += __shfl_xor(sum, off);
    if (lane == 0) c1[o] = sum + b1[o];
}

__global__ void wn_scale_kernel(const float* __restrict__ v, const float* __restrict__ g,
                                float* __restrict__ s, int K, int R) {
    int r = (blockIdx.x * blockDim.x + threadIdx.x) >> 6;
    int lane = threadIdx.x & 63;
    if (r >= R) return;
    const float* vr = v + (size_t)r * K;
    float sum = 0.f;
    for (int k = lane; k < K; k += 64) { float x = vr[k]; sum = fmaf(x, x, sum); }
    #pragma unroll
    for (int off = 32; off; off >>= 1) sum += __shfl_xor(sum, off);
    if (lane == 0) s[r] = g[r] / sqrtf(sum);
}

// ---------------------------------------------------------------------------
// Px[t][o] = c1[o] + sum_k sg[t][2k]   * w1[o][2k]
// Py[t][o] =         sum_k sg[t][2k+1] * w1[o][2k+1]
// ---------------------------------------------------------------------------
__global__ void pxy_kernel(const float* __restrict__ sg, const float* __restrict__ w1,
                           const float* __restrict__ c1, float* __restrict__ Px,
                           float* __restrict__ Py) {
    int idx = blockIdx.x * 256 + threadIdx.x;  // 256*1024
    int t = idx >> 10, o = idx & 1023;
    const float* wr = w1 + (size_t)o * 2080;
    const float* sr = sg + t * 32;
    float px = 0.f, py = 0.f;
    #pragma unroll
    for (int k = 0; k < 16; ++k) {
        px = fmaf(sr[2 * k], wr[2 * k], px);
        py = fmaf(sr[2 * k + 1], wr[2 * k + 1], py);
    }
    Px[idx] = px + c1[o];
    Py[idx] = py;
}

// Qx/Qy for w2 (512 outputs, ld 1056)
__global__ void qxy_kernel(const float* __restrict__ sg, const float* __restrict__ w2,
                           float* __restrict__ Qx, float* __restrict__ Qy) {
    int idx = blockIdx.x * 256 + threadIdx.x;  // 256*512
    int t = idx >> 9, o = idx & 511;
    const float* wr = w2 + (size_t)o * 1056;
    const float* sr = sg + t * 32;
    float qx = 0.f, qy = 0.f;
    #pragma unroll
    for (int k = 0; k < 16; ++k) {
        qx = fmaf(sr[2 * k], wr[2 * k], qx);
        qy = fmaf(sr[2 * k + 1], wr[2 * k + 1], qy);
    }
    Qx[idx] = qx;
    Qy[idx] = qy;
}

// ---------------------------------------------------------------------------
// float -> bf16 weight conversion
// ---------------------------------------------------------------------------
__global__ void cvt_bf16_kernel(const float* __restrict__ src, unsigned short* __restrict__ dst, int n) {
    int i = blockIdx.x * 256 + threadIdx.x;
    if (i < n) dst[i] = f2bf(src[i]);
}
__global__ void cvt_w2_kernel(const float* __restrict__ w2, unsigned short* __restrict__ dst) {
    int i = blockIdx.x * 256 + threadIdx.x;   // 512*1024
    int r = i >> 10, c = i & 1023;
    dst[i] = f2bf(w2[(size_t)r * 1056 + 32 + c]);
}

// ---------------------------------------------------------------------------
// mid init: mid[n][o] = lrelu(Px[i][o] + Py[j][o]), split hi/lo
// ---------------------------------------------------------------------------
__global__ void mid_init_kernel(const float* __restrict__ Px, const float* __restrict__ Py,
                                unsigned short* __restrict__ hi, unsigned short* __restrict__ lo,
                                int n0, int CH) {
    int idx = blockIdx.x * 256 + threadIdx.x;       // CH*1024
    if (idx >= CH * 1024) return;
    int n = n0 + (idx >> 10), o = idx & 1023;
    int i = n >> 8, j = n & 255;
    float v = Px[i * 1024 + o] + Py[j * 1024 + o];
    v = LRELU(v);
    split_write(v, hi + idx, lo + idx);
}

// h2 init: h2[n][o] = Qx[i][o] + Qy[j][o]  (no act; act comes in w2 GEMM)
__global__ void h2_init_kernel(const float* __restrict__ Qx, const float* __restrict__ Qy,
                               unsigned short* __restrict__ hi, unsigned short* __restrict__ lo,
                               int n0, int CH) {
    int idx = blockIdx.x * 256 + threadIdx.x;       // CH*512
    if (idx >= CH * 512) return;
    int n = n0 + (idx >> 9), o = idx & 511;
    int i = n >> 8, j = n & 255;
    float v = Qx[i * 512 + o] + Qy[j * 512 + o];
    split_write(v, hi + idx, lo + idx);
}

// ---------------------------------------------------------------------------
// bf16 MFMA GEMM: D(hi/lo split) <= A[M,K]bf16 * B[N,K]bf16^T  (m97 structure)
// 128x128 tile, BK=64, 4 waves, 4x4 of 16x16x32 MFMA.
// ---------------------------------------------------------------------------
__global__ __launch_bounds__(256) void gemm_mfma(
    const unsigned short* __restrict__ A, int lda,
    const unsigned short* __restrict__ B, int ldb,
    unsigned short* __restrict__ Dhi, unsigned short* __restrict__ Dlo, int ldd,
    const float* __restrict__ scale, const float* __restrict__ bias,
    int K, int mode, int act) {
    __shared__ unsigned short As[128 * 64];
    __shared__ unsigned short Bs[128 * 64];
    int tid = threadIdx.x;
    int wid = tid >> 6, lane = tid & 63;
    int wy = wid & 1, wx = wid >> 1;
    int frow = lane & 15, fquad = lane >> 4;
    int bm = blockIdx.x, bn = blockIdx.y;
    const unsigned short* Ab = A + (size_t)bm * 128 * lda;
    const unsigned short* Bb = B + (size_t)bn * 128 * ldb;

    f32x4 acc[4][4] = {};

    for (int k0 = 0; k0 < K; k0 += 64) {
        __syncthreads();
        #pragma unroll
        for (int q = 0; q < 4; ++q) {
            int c = (wid * 4 + q) * 64 + lane;
            int row = c >> 3, col8 = (c & 7) * 8;
            load_lds16(Ab + (size_t)row * lda + k0 + col8, (void*)(As + (size_t)(wid * 4 + q) * 512));
        }
        #pragma unroll
        for (int q = 0; q < 4; ++q) {
            int c = (wid * 4 + q) * 64 + lane;
            int row = c >> 3, col8 = (c & 7) * 8;
            load_lds16(Bb + (size_t)row * ldb + k0 + col8, (void*)(Bs + (size_t)(wid * 4 + q) * 512));
        }
        __syncthreads();
        #pragma unroll
        for (int ks = 0; ks < 64; ks += 32) {
            short8 af[4], bfr[4];
            #pragma unroll
            for (int i = 0; i < 4; ++i)
                af[i] = *(const short8*)(As + (size_t)(wy * 64 + i * 16 + frow) * 64 + ks + fquad * 8);
            #pragma unroll
            for (int j = 0; j < 4; ++j)
                bfr[j] = *(const short8*)(Bs + (size_t)(wx * 64 + j * 16 + frow) * 64 + ks + fquad * 8);
            #pragma unroll
            for (int i = 0; i < 4; ++i)
                #pragma unroll
                for (int j = 0; j < 4; ++j)
                    acc[i][j] = __builtin_amdgcn_mfma_f32_16x16x32_bf16(af[i], bfr[j], acc[i][j], 0, 0, 0);
        }
    }

    #pragma unroll
    for (int i = 0; i < 4; ++i) {
        #pragma unroll
        for (int j = 0; j < 4; ++j) {
            int n = bn * 128 + wx * 64 + j * 16 + frow;
            float sc = scale ? scale[n] : 1.0f;
            float bi = bias ? bias[n] : 0.0f;
            #pragma unroll
            for (int r = 0; r < 4; ++r) {
                int m = bm * 128 + wy * 64 + i * 16 + fquad * 4 + r;
                size_t di = (size_t)m * ldd + n;
                float v = acc[i][j][r] * sc + bi;
                if (mode == MODE_ADD_BEFORE) v += bf2f(Dhi[di]) + bf2f(Dlo[di]);
                if (act) v = LRELU(v);
                if (mode == MODE_ADD_AFTER) v += bf2f(Dhi[di]) + bf2f(Dlo[di]);
                split_write(v, Dhi + di, Dlo + di);
            }
        }
    }
}

// ---------------------------------------------------------------------------
// Final layer: out[c, n0+m] = 1.1*sigmoid(h[m].w3[c] + b3[c]) - 0.05
// ---------------------------------------------------------------------------
__global__ void rgb_kernel(const unsigned short* __restrict__ Hhi,
                           const unsigned short* __restrict__ Hlo,
                           const float* __restrict__ w3,
                           const float* __restrict__ b3, float* __restrict__ out,
                           int n0, int Nc) {
    int m = (blockIdx.x * blockDim.x + threadIdx.x) >> 6;
    int lane = threadIdx.x & 63;
    if (m >= Nc) return;
    const unsigned short* hh = Hhi + (size_t)m * 512;
    const unsigned short* hl = Hlo + (size_t)m * 512;
    float s0 = 0.f, s1 = 0.f, s2 = 0.f;
    for (int k = lane; k < 512; k += 64) {
        float hv = bf2f(hh[k]) + bf2f(hl[k]);
        s0 = fmaf(hv, w3[k], s0);
        s1 = fmaf(hv, w3[512 + k], s1);
        s2 = fmaf(hv, w3[1024 + k], s2);
    }
    #pragma unroll
    for (int off = 32; off; off >>= 1) {
        s0 += __shfl_xor(s0, off);
        s1 += __shfl_xor(s1, off);
        s2 += __shfl_xor(s2, off);
    }
    if (lane == 0) {
        float v[3] = {s0 + b3[0], s1 + b3[1], s2 + b3[2]};
        #pragma unroll
        for (int c = 0; c < 3; ++c) {
            float sg = 1.0f / (1.0f + expf(-v[c]));
            out[(size_t)c * 65536 + n0 + m] = 1.1f * sg - 0.05f;
        }
    }
}

extern "C" void kernel_launch(void* const* d_in, const int* in_sizes, int n_in,
                              void* d_out, int out_size, void* d_ws, size_t ws_size,
                              hipStream_t stream) {
    const float* feature = (const float*)d_in[0];
    const float* cw1 = (const float*)d_in[1];  const float* cb1 = (const float*)d_in[2];
    const float* cw2 = (const float*)d_in[3];  const float* cb2 = (const float*)d_in[4];
    const float* cw3 = (const float*)d_in[5];  const float* cb3 = (const float*)d_in[6];
    const float* cw4 = (const float*)d_in[7];  const float* cb4 = (const float*)d_in[8];
    const float* cw5 = (const float*)d_in[9];  const float* cb5 = (const float*)d_in[10];
    const float* w1  = (const float*)d_in[11]; const float* b1  = (const float*)d_in[12];
    const float* m1_vf = (const float*)d_in[13]; const float* m1_gf = (const float*)d_in[14];
    const float* m1_bf = (const float*)d_in[15];
    const float* m1_vg = (const float*)d_in[16]; const float* m1_gg = (const float*)d_in[17];
    const float* m1_bg = (const float*)d_in[18];
    const float* w2  = (const float*)d_in[19]; const float* b2  = (const float*)d_in[20];
    const float* m2_vf = (const float*)d_in[21]; const float* m2_gf = (const float*)d_in[22];
    const float* m2_bf = (const float*)d_in[23];
    const float* m2_vg = (const float*)d_in[24]; const float* m2_gg = (const float*)d_in[25];
    const float* m2_bg = (const float*)d_in[26];
    const float* w3  = (const float*)d_in[27]; const float* b3  = (const float*)d_in[28];
    float* out = (float*)d_out;

    float* ws = (float*)d_ws;
    size_t off = 0;
    float* sgrid   = ws + off; off += 256 * 32;
    float* cbA     = ws + off; off += 768 * 64;
    float* cbB     = ws + off; off += 768 * 64;
    float* featbuf = ws + off; off += 2048;
    float* c1      = ws + off; off += 1024;
    float* s1f     = ws + off; off += 8 * 512;
    float* s1g     = ws + off; off += 8 * 512;
    float* s2f     = ws + off; off += 8 * 256;
    float* s2g     = ws + off; off += 8 * 256;
    float* Px      = ws + off; off += 256 * 1024;
    float* Py      = ws + off; off += 256 * 1024;
    float* Qx      = ws + off; off += 256 * 512;
    float* Qy      = ws + off; off += 256 * 512;
    unsigned short* m1f_bf = (unsigned short*)(ws + off); off += (size_t)8 * 512 * 512 / 2;
    unsigned short* m1g_bf = (unsigned short*)(ws + off); off += (size_t)8 * 512 * 512 / 2;
    unsigned short* m2f_bf = (unsigned short*)(ws + off); off += (size_t)8 * 256 * 256 / 2;
    unsigned short* m2g_bf = (unsigned short*)(ws + off); off += (size_t)8 * 256 * 256 / 2;
    unsigned short* w2m_bf = (unsigned short*)(ws + off); off += (size_t)512 * 1024 / 2;
    size_t fixedF = off;

    // activations: hi/lo bf16 planes; per row 1024+1024+512+512 ushorts = 1536 floats
    int CH = 16384;   // capped for LLC residency
    while (CH > 1024 && (fixedF + (size_t)CH * 1536) * sizeof(float) > ws_size) CH >>= 1;
    unsigned short* mid_hi = (unsigned short*)(ws + fixedF);
    unsigned short* mid_lo = mid_hi + (size_t)CH * 1024;
    unsigned short* h2_hi  = mid_lo + (size_t)CH * 1024;
    unsigned short* h2_lo  = h2_hi + (size_t)CH * 512;

    // ---- constants ----
    sgrid_kernel<<<32, 256, 0, stream>>>(sgrid);
    wn_scale_kernel<<<(8 * 512) / 4, 256, 0, stream>>>(m1_vf, m1_gf, s1f, 512, 8 * 512);
    wn_scale_kernel<<<(8 * 512) / 4, 256, 0, stream>>>(m1_vg, m1_gg, s1g, 512, 8 * 512);
    wn_scale_kernel<<<(8 * 256) / 4, 256, 0, stream>>>(m2_vf, m2_gf, s2f, 256, 8 * 256);
    wn_scale_kernel<<<(8 * 256) / 4, 256, 0, stream>>>(m2_vg, m2_gg, s2g, 256, 8 * 256);
    {
        int n1 = 8 * 512 * 512, n2 = 8 * 256 * 256, n3 = 512 * 1024;
        cvt_bf16_kernel<<<(n1 + 255) / 256, 256, 0, stream>>>(m1_vf, m1f_bf, n1);
        cvt_bf16_kernel<<<(n1 + 255) / 256, 256, 0, stream>>>(m1_vg, m1g_bf, n1);
        cvt_bf16_kernel<<<(n2 + 255) / 256, 256, 0, stream>>>(m2_vf, m2f_bf, n2);
        cvt_bf16_kernel<<<(n2 + 255) / 256, 256, 0, stream>>>(m2_vg, m2g_bf, n2);
        cvt_w2_kernel<<<(n3 + 255) / 256, 256, 0, stream>>>(w2, w2m_bf);
    }

    // ---- conv trunk: zero -> partial (atomic) -> finalize ----
    hipMemsetAsync(cbA, 0, 768 * 64 * sizeof(float), stream);
    conv_partial<<<dim3(768, 28), 64, 0, stream>>>(feature, cw1, cbA, 448, 192, 8, 1);
    conv_finalize<<<(768 * 64) / 256, 256, 0, stream>>>(cbA, cb1, 64, 768 * 64);
    hipMemsetAsync(cbB, 0, 768 * 64 * sizeof(float), stream);
    conv_partial<<<dim3(768, 16), 64, 0, stream>>>(cbA, cw2, cbB, 256, 256, 8, 1);
    conv_finalize<<<(768 * 64) / 256, 256, 0, stream>>>(cbB, cb2, 64, 768 * 64);
    hipMemsetAsync(cbA, 0, 768 * 64 * sizeof(float), stream);
    conv_partial<<<dim3(768, 24), 64, 0, stream>>>(cbB, cw3, cbA, 384, 384, 8, 1);
    conv_finalize<<<(768 * 64) / 256, 256, 0, stream>>>(cbA, cb3, 64, 768 * 64);
    hipMemsetAsync(cbB, 0, 768 * 36 * sizeof(float), stream);
    conv_partial<<<dim3(768, 16), 64, 0, stream>>>(cbA, cw4, cbB, 256, 256, 8, 0);   // ->6x6
    conv_finalize<<<(768 * 36 + 255) / 256, 256, 0, stream>>>(cbB, cb4, 36, 768 * 36);
    hipMemsetAsync(featbuf, 0, 2048 * sizeof(float), stream);
    conv_partial<<<dim3(128, 48), 64, 0, stream>>>(cbB, cw5, featbuf, 768, 128, 6, 0); // ->4x4
    conv_finalize<<<(2048 + 255) / 256, 256, 0, stream>>>(featbuf, cb5, 16, 2048);

    // ---- c1, Px/Py, Qx/Qy ----
    feat_c1_kernel<<<1024 / 4, 256, 0, stream>>>(featbuf, w1, b1, c1);
    pxy_kernel<<<(256 * 1024) / 256, 256, 0, stream>>>(sgrid, w1, c1, Px, Py);
    qxy_kernel<<<(256 * 512) / 256, 256, 0, stream>>>(sgrid, w2, Qx, Qy);

    // ---- per-position MLP in chunks ----
    for (int n0 = 0; n0 < 65536; n0 += CH) {
        mid_init_kernel<<<(CH * 1024) / 256, 256, 0, stream>>>(Px, Py, mid_hi, mid_lo, n0, CH);
        for (int t = 0; t < 8; ++t) {
            gemm_mfma<<<dim3(CH / 128, 4), 256, 0, stream>>>(
                mid_hi + 512, 1024, m1f_bf + (size_t)t * 512 * 512, 512,
                mid_hi, mid_lo, 1024, s1f + t * 512, m1_bf + t * 512, 512, MODE_ADD_AFTER, 1);
            gemm_mfma<<<dim3(CH / 128, 4), 256, 0, stream>>>(
                mid_hi, 1024, m1g_bf + (size_t)t * 512 * 512, 512,
                mid_hi + 512, mid_lo + 512, 1024, s1g + t * 512, m1_bg + t * 512, 512, MODE_ADD_AFTER, 1);
        }
        h2_init_kernel<<<(CH * 512) / 256, 256, 0, stream>>>(Qx, Qy, h2_hi, h2_lo, n0, CH);
        gemm_mfma<<<dim3(CH / 128, 4), 256, 0, stream>>>(
            mid_hi, 1024, w2m_bf, 1024, h2_hi, h2_lo, 512, nullptr, b2, 1024, MODE_ADD_BEFORE, 1);
        for (int t = 0; t < 8; ++t) {
            gemm_mfma<<<dim3(CH / 128, 2), 256, 0, stream>>>(
                h2_hi + 256, 512, m2f_bf + (size_t)t * 256 * 256, 256,
                h2_hi, h2_lo, 512, s2f + t * 256, m2_bf + t * 256, 256, MODE_ADD_AFTER, 1);
            gemm_mfma<<<dim3(CH / 128, 2), 256, 0, stream>>>(
                h2_hi, 512, m2g_bf + (size_t)t * 256 * 256, 256,
                h2_hi + 256, h2_lo + 256, 512, s2g + t * 256, m2_bg + t * 256, 256, MODE_ADD_AFTER, 1);
        }
        rgb_kernel<<<CH / 4, 256, 0, stream>>>(h2_hi, h2_lo, w3, b3, out, n0, CH);
    }
}

// Round 4
// 2384.393 us; speedup vs baseline: 6.0304x; 2.0243x over previous
//
#include <hip/hip_runtime.h>
#include <cmath>

#define LRELU(x) ((x) > 0.0f ? (x) : 0.01f * (x))

typedef __attribute__((ext_vector_type(8))) short short8;
typedef __attribute__((ext_vector_type(4))) float f32x4;

constexpr int RS = 1032;   // LDS master row stride in elems (+8 pad: conflict-free b128)

__device__ __forceinline__ unsigned short f2bf(float f) {
    unsigned u = __float_as_uint(f);
    unsigned r = (u + 0x7fff + ((u >> 16) & 1)) >> 16;   // RNE
    return (unsigned short)r;
}
__device__ __forceinline__ float bf2f(unsigned short h) {
    return __uint_as_float((unsigned)h << 16);
}

// ---------------------------------------------------------------------------
// sgrid[t][c] = sin(r_t * 2^((c/2)/2)), r_t=(t-128)*pi/256  (256 x 32)
// ---------------------------------------------------------------------------
__global__ void sgrid_kernel(float* __restrict__ sg) {
    int idx = blockIdx.x * blockDim.x + threadIdx.x;
    if (idx >= 256 * 32) return;
    int t = idx >> 5, c = idx & 31;
    double r = (double)(t - 128) * 3.14159265358979323846 / 256.0;
    double scale = exp2(0.5 * (double)(c >> 1));
    sg[idx] = (float)sin(r * scale);
}

// ---------------------------------------------------------------------------
// Grouped 3x3 conv + lrelu. Block per oc; weights staged coalesced into LDS
// (fixes the 175 GB/s scalar weight-fetch pathology); 64 px x 4 ic-chunks.
// ---------------------------------------------------------------------------
__global__ __launch_bounds__(256) void conv_lds(
    const float* __restrict__ x, const float* __restrict__ w,
    const float* __restrict__ bias, float* __restrict__ y,
    int Cin_g, int Cout_g, int Hin, int pad) {
    __shared__ float wsh[6912];
    __shared__ float red[256];
    int oc = blockIdx.x;
    int Hout = pad ? Hin : Hin - 2;
    int t = threadIdx.x;
    int nw = Cin_g * 9;
    const float* wb = w + (size_t)oc * nw;
    for (int idx = t; idx < nw; idx += 256) wsh[idx] = wb[idx];
    __syncthreads();
    int p = t & 63, ch = t >> 6;
    int oy = p / Hout, ox = p % Hout;
    int g = oc / Cout_g;
    const float* xb = x + (size_t)g * Cin_g * Hin * Hin;
    bool valid = p < Hout * Hout;
    int S = (Cin_g + 3) >> 2;
    int ic0 = ch * S, ic1 = min(Cin_g, ic0 + S);
    float acc = 0.f;
    if (valid) {
        for (int ic = ic0; ic < ic1; ++ic) {
            const float* xc = xb + (size_t)ic * Hin * Hin;
            const float* wc = wsh + ic * 9;
            #pragma unroll
            for (int ky = 0; ky < 3; ++ky) {
                int iy = oy + ky - pad;
                if (iy < 0 || iy >= Hin) continue;
                #pragma unroll
                for (int kx = 0; kx < 3; ++kx) {
                    int ix = ox + kx - pad;
                    if (ix < 0 || ix >= Hin) continue;
                    acc = fmaf(xc[iy * Hin + ix], wc[ky * 3 + kx], acc);
                }
            }
        }
    }
    red[t] = acc;
    __syncthreads();
    if (t < 64 && valid) {
        float s = red[t] + red[t + 64] + red[t + 128] + red[t + 192] + bias[oc];
        y[(size_t)oc * Hout * Hout + p] = LRELU(s);
    }
}

// ---------------------------------------------------------------------------
// c1[o] = b1[o] + feat . w1[o][32:]
// ---------------------------------------------------------------------------
__global__ void feat_c1_kernel(const float* __restrict__ feat, const float* __restrict__ w1,
                               const float* __restrict__ b1, float* __restrict__ c1) {
    int o = (blockIdx.x * blockDim.x + threadIdx.x) >> 6;
    int lane = threadIdx.x & 63;
    if (o >= 1024) return;
    const float* wr = w1 + (size_t)o * 2080 + 32;
    float sum = 0.f;
    for (int k = lane; k < 2048; k += 64) sum += feat[k] * wr[k];
    #pragma unroll
    for (int off = 32; off; off >>= 1) sum += __shfl_xor(sum, off);
    if (lane == 0) c1[o] = sum + b1[o];
}

// ---------------------------------------------------------------------------
// wn_cvt: one block per row; writes bf16 copy of v and s = g/||v|| in one pass
// ---------------------------------------------------------------------------
__global__ __launch_bounds__(256) void wn_cvt(const float* __restrict__ v, const float* __restrict__ g,
                                              unsigned short* __restrict__ vbf, float* __restrict__ s,
                                              int K) {
    __shared__ float red[256];
    int r = blockIdx.x, t = threadIdx.x;
    const float* vr = v + (size_t)r * K;
    float sum = 0.f;
    for (int k = t; k < K; k += 256) {
        float x = vr[k];
        sum = fmaf(x, x, sum);
        vbf[(size_t)r * K + k] = f2bf(x);
    }
    red[t] = sum;
    __syncthreads();
    for (int o = 128; o; o >>= 1) {
        if (t < o) red[t] += red[t + o];
        __syncthreads();
    }
    if (t == 0) s[r] = g[r] / sqrtf(red[0]);
}

// w2[:, 32:] (512 x 1024 of ld 1056) -> bf16
__global__ void cvt_w2_kernel(const float* __restrict__ w2, unsigned short* __restrict__ dst) {
    int i = blockIdx.x * 256 + threadIdx.x;
    int r = i >> 10, c = i & 1023;
    dst[i] = f2bf(w2[(size_t)r * 1056 + 32 + c]);
}

// ---------------------------------------------------------------------------
// Px[t][o] = c1[o] + sum_k sg[t][2k]*w1[o][2k] ; Py[t][o] = odd part
// ---------------------------------------------------------------------------
__global__ void pxy_kernel(const float* __restrict__ sg, const float* __restrict__ w1,
                           const float* __restrict__ c1, float* __restrict__ Px,
                           float* __restrict__ Py) {
    int idx = blockIdx.x * 256 + threadIdx.x;  // 256*1024
    int t = idx >> 10, o = idx & 1023;
    const float* wr = w1 + (size_t)o * 2080;
    const float* sr = sg + t * 32;
    float px = 0.f, py = 0.f;
    #pragma unroll
    for (int k = 0; k < 16; ++k) {
        px = fmaf(sr[2 * k], wr[2 * k], px);
        py = fmaf(sr[2 * k + 1], wr[2 * k + 1], py);
    }
    Px[idx] = px + c1[o];
    Py[idx] = py;
}

__global__ void qxy_kernel(const float* __restrict__ sg, const float* __restrict__ w2,
                           float* __restrict__ Qx, float* __restrict__ Qy) {
    int idx = blockIdx.x * 256 + threadIdx.x;  // 256*512
    int t = idx >> 9, o = idx & 511;
    const float* wr = w2 + (size_t)o * 1056;
    const float* sr = sg + t * 32;
    float qx = 0.f, qy = 0.f;
    #pragma unroll
    for (int k = 0; k < 16; ++k) {
        qx = fmaf(sr[2 * k], wr[2 * k], qx);
        qy = fmaf(sr[2 * k + 1], wr[2 * k + 1], qy);
    }
    Qx[idx] = qx;
    Qy[idx] = qy;
}

// ---------------------------------------------------------------------------
// Fused MLP: one persistent block owns 64 rows; master activation (bf16 hi)
// lives in LDS [64][RS]; stack-1 lo plane in VGPRs; stack-2 hi+lo in LDS.
// All 33 GEMM steps run in-block; only weights stream from global (L2/LLC).
// ---------------------------------------------------------------------------

// stack-1 step: out cols [dst+w*64..+64) += via K=512 GEMM from cols [src..+512)
__device__ __forceinline__ void step1(unsigned short* sm, int w, int l15, int lq,
                                      int src, int dst,
                                      const unsigned short* __restrict__ B,
                                      const float* __restrict__ sc,
                                      const float* __restrict__ bi,
                                      unsigned* lo_pk) {
    f32x4 acc[4][4] = {};
    const unsigned short* bbase = B + (size_t)(w * 64 + l15) * 512 + lq * 8;
    const unsigned short* abase = sm + (size_t)l15 * RS + src + lq * 8;
    short8 bcur[4];
    #pragma unroll
    for (int nt = 0; nt < 4; ++nt) bcur[nt] = *(const short8*)(bbase + nt * 16 * 512);
    for (int kc = 0; kc < 16; ++kc) {
        short8 bnxt[4];
        if (kc < 15) {
            #pragma unroll
            for (int nt = 0; nt < 4; ++nt)
                bnxt[nt] = *(const short8*)(bbase + nt * 16 * 512 + (kc + 1) * 32);
        }
        short8 af[4];
        #pragma unroll
        for (int mt = 0; mt < 4; ++mt)
            af[mt] = *(const short8*)(abase + (size_t)mt * 16 * RS + kc * 32);
        #pragma unroll
        for (int mt = 0; mt < 4; ++mt)
            #pragma unroll
            for (int nt = 0; nt < 4; ++nt)
                acc[mt][nt] = __builtin_amdgcn_mfma_f32_16x16x32_bf16(af[mt], bcur[nt], acc[mt][nt], 0, 0, 0);
        #pragma unroll
        for (int nt = 0; nt < 4; ++nt) bcur[nt] = bnxt[nt];
    }
    #pragma unroll
    for (int nt = 0; nt < 4; ++nt) {
        int nh = w * 64 + nt * 16 + l15;
        float s = sc[nh], b = bi[nh];
        int col = dst + nh;
        #pragma unroll
        for (int mt = 0; mt < 4; ++mt) {
            #pragma unroll
            for (int r = 0; r < 4; ++r) {
                int row = mt * 16 + lq * 4 + r;
                float v = acc[mt][nt][r] * s + b;
                v = LRELU(v);
                unsigned& pk = lo_pk[mt * 8 + nt * 2 + (r >> 1)];
                unsigned short lov = (r & 1) ? (unsigned short)(pk >> 16) : (unsigned short)(pk & 0xffffu);
                unsigned short hv = sm[(size_t)row * RS + col];
                v += bf2f(hv) + bf2f(lov);
                unsigned short nhv = f2bf(v);
                sm[(size_t)row * RS + col] = nhv;
                unsigned short nlo = f2bf(v - bf2f(nhv));
                pk = (r & 1) ? ((pk & 0xffffu) | ((unsigned)nlo << 16))
                             : ((pk & 0xffff0000u) | (unsigned)nlo);
            }
        }
    }
}

// stack-2 step: hi at cols [0..512), lo at cols [512..1024) of the LDS master
__device__ __forceinline__ void step2(unsigned short* sm, int w, int l15, int lq,
                                      int src, int dst,
                                      const unsigned short* __restrict__ B,
                                      const float* __restrict__ sc,
                                      const float* __restrict__ bi) {
    f32x4 acc[4][2] = {};
    const unsigned short* bbase = B + (size_t)(w * 32 + l15) * 256 + lq * 8;
    const unsigned short* abase = sm + (size_t)l15 * RS + src + lq * 8;
    short8 bcur[2];
    #pragma unroll
    for (int nt = 0; nt < 2; ++nt) bcur[nt] = *(const short8*)(bbase + nt * 16 * 256);
    for (int kc = 0; kc < 8; ++kc) {
        short8 bnxt[2];
        if (kc < 7) {
            #pragma unroll
            for (int nt = 0; nt < 2; ++nt)
                bnxt[nt] = *(const short8*)(bbase + nt * 16 * 256 + (kc + 1) * 32);
        }
        short8 af[4];
        #pragma unroll
        for (int mt = 0; mt < 4; ++mt)
            af[mt] = *(const short8*)(abase + (size_t)mt * 16 * RS + kc * 32);
        #pragma unroll
        for (int mt = 0; mt < 4; ++mt)
            #pragma unroll
            for (int nt = 0; nt < 2; ++nt)
                acc[mt][nt] = __builtin_amdgcn_mfma_f32_16x16x32_bf16(af[mt], bcur[nt], acc[mt][nt], 0, 0, 0);
        #pragma unroll
        for (int nt = 0; nt < 2; ++nt) bcur[nt] = bnxt[nt];
    }
    #pragma unroll
    for (int nt = 0; nt < 2; ++nt) {
        int nh = w * 32 + nt * 16 + l15;
        float s = sc[nh], b = bi[nh];
        int col = dst + nh;
        #pragma unroll
        for (int mt = 0; mt < 4; ++mt) {
            #pragma unroll
            for (int r = 0; r < 4; ++r) {
                int row = mt * 16 + lq * 4 + r;
                float v = acc[mt][nt][r] * s + b;
                v = LRELU(v);
                size_t hidx = (size_t)row * RS + col;
                v += bf2f(sm[hidx]) + bf2f(sm[hidx + 512]);
                unsigned short nhv = f2bf(v);
                sm[hidx] = nhv;
                sm[hidx + 512] = f2bf(v - bf2f(nhv));
            }
        }
    }
}

__global__ __launch_bounds__(512, 2) void fused_mlp(
    const float* __restrict__ Px, const float* __restrict__ Py,
    const float* __restrict__ Qx, const float* __restrict__ Qy,
    const unsigned short* __restrict__ m1f, const float* __restrict__ s1f, const float* __restrict__ bf1,
    const unsigned short* __restrict__ m1g, const float* __restrict__ s1g, const float* __restrict__ bg1,
    const unsigned short* __restrict__ w2m, const float* __restrict__ b2,
    const unsigned short* __restrict__ m2f, const float* __restrict__ s2f, const float* __restrict__ bf2_,
    const unsigned short* __restrict__ m2g, const float* __restrict__ s2g, const float* __restrict__ bg2_,
    const float* __restrict__ w3, const float* __restrict__ b3,
    float* __restrict__ out) {
    extern __shared__ unsigned short sm[];     // [64][RS]
    int tid = threadIdx.x;
    int w = tid >> 6, l = tid & 63;
    int l15 = l & 15, lq = l >> 4;
    int n0 = blockIdx.x * 64;
    int i = n0 >> 8;

    unsigned lo_pk[64];   // stack-1 lo plane: [half][mt][nt][r-pair], fully unrolled idx

    // ---- P1: mid init: v = lrelu(Px[i]+Py[j]); hi->LDS, lo->VGPR ----
    #pragma unroll
    for (int h = 0; h < 2; ++h) {
        #pragma unroll
        for (int nt = 0; nt < 4; ++nt) {
            int col = h * 512 + w * 64 + nt * 16 + l15;
            float px = Px[(size_t)i * 1024 + col];
            #pragma unroll
            for (int mt = 0; mt < 4; ++mt) {
                #pragma unroll
                for (int r = 0; r < 4; ++r) {
                    int row = mt * 16 + lq * 4 + r;
                    int j = (n0 + row) & 255;
                    float v = px + Py[(size_t)j * 1024 + col];
                    v = LRELU(v);
                    unsigned short hv = f2bf(v);
                    sm[(size_t)row * RS + col] = hv;
                    unsigned short lov = f2bf(v - bf2f(hv));
                    unsigned& pk = lo_pk[h * 32 + mt * 8 + nt * 2 + (r >> 1)];
                    pk = (r & 1) ? ((pk & 0xffffu) | ((unsigned)lov << 16))
                                 : ((pk & 0xffff0000u) | (unsigned)lov);
                }
            }
        }
    }
    __syncthreads();

    // ---- P2: stack 1, 8 x (F then G) ----
    for (int t = 0; t < 8; ++t) {
        step1(sm, w, l15, lq, 512, 0, m1f + (size_t)t * 512 * 512, s1f + t * 512, bf1 + t * 512, lo_pk);
        __syncthreads();
        step1(sm, w, l15, lq, 0, 512, m1g + (size_t)t * 512 * 512, s1g + t * 512, bg1 + t * 512, lo_pk + 32);
        __syncthreads();
    }

    // ---- P3: h2 = lrelu(Qx+Qy + mid @ w2m^T + b2); overwrite master ----
    {
        f32x4 acc[4][4] = {};
        const unsigned short* bbase = w2m + (size_t)(w * 64 + l15) * 1024 + lq * 8;
        const unsigned short* abase = sm + (size_t)l15 * RS + lq * 8;
        short8 bcur[4];
        #pragma unroll
        for (int nt = 0; nt < 4; ++nt) bcur[nt] = *(const short8*)(bbase + nt * 16 * 1024);
        for (int kc = 0; kc < 32; ++kc) {
            short8 bnxt[4];
            if (kc < 31) {
                #pragma unroll
                for (int nt = 0; nt < 4; ++nt)
                    bnxt[nt] = *(const short8*)(bbase + nt * 16 * 1024 + (kc + 1) * 32);
            }
            short8 af[4];
            #pragma unroll
            for (int mt = 0; mt < 4; ++mt)
                af[mt] = *(const short8*)(abase + (size_t)mt * 16 * RS + kc * 32);
            #pragma unroll
            for (int mt = 0; mt < 4; ++mt)
                #pragma unroll
                for (int nt = 0; nt < 4; ++nt)
                    acc[mt][nt] = __builtin_amdgcn_mfma_f32_16x16x32_bf16(af[mt], bcur[nt], acc[mt][nt], 0, 0, 0);
            #pragma unroll
            for (int nt = 0; nt < 4; ++nt) bcur[nt] = bnxt[nt];
        }
        __syncthreads();   // all reads of master1 done before overwrite
        #pragma unroll
        for (int nt = 0; nt < 4; ++nt) {
            int col = w * 64 + nt * 16 + l15;          // 0..511
            float qx = Qx[(size_t)i * 512 + col];
            float bb = b2[col];
            #pragma unroll
            for (int mt = 0; mt < 4; ++mt) {
                #pragma unroll
                for (int r = 0; r < 4; ++r) {
                    int row = mt * 16 + lq * 4 + r;
                    int j = (n0 + row) & 255;
                    float v = acc[mt][nt][r] + qx + Qy[(size_t)j * 512 + col] + bb;
                    v = LRELU(v);
                    size_t hidx = (size_t)row * RS + col;
                    unsigned short hv = f2bf(v);
                    sm[hidx] = hv;
                    sm[hidx + 512] = f2bf(v - bf2f(hv));
                }
            }
        }
    }
    __syncthreads();

    // ---- P4: stack 2, 8 x (F then G) ----
    for (int t = 0; t < 8; ++t) {
        step2(sm, w, l15, lq, 256, 0, m2f + (size_t)t * 256 * 256, s2f + t * 256, bf2_ + t * 256);
        __syncthreads();
        step2(sm, w, l15, lq, 0, 256, m2g + (size_t)t * 256 * 256, s2g + t * 256, bg2_ + t * 256);
        __syncthreads();
    }

    // ---- P5: rgb: out[c][n] = 1.1*sigmoid(h2 . w3[c] + b3[c]) - 0.05 ----
    #pragma unroll
    for (int rr = 0; rr < 8; ++rr) {
        int row = w * 8 + rr;
        float s0 = 0.f, s1 = 0.f, s2 = 0.f;
        #pragma unroll
        for (int it = 0; it < 8; ++it) {
            int k = it * 64 + l;
            size_t hidx = (size_t)row * RS + k;
            float hv = bf2f(sm[hidx]) + bf2f(sm[hidx + 512]);
            s0 = fmaf(hv, w3[k], s0);
            s1 = fmaf(hv, w3[512 + k], s1);
            s2 = fmaf(hv, w3[1024 + k], s2);
        }
        #pragma unroll
        for (int off = 32; off; off >>= 1) {
            s0 += __shfl_xor(s0, off);
            s1 += __shfl_xor(s1, off);
            s2 += __shfl_xor(s2, off);
        }
        if (l == 0) {
            float v[3] = {s0 + b3[0], s1 + b3[1], s2 + b3[2]};
            #pragma unroll
            for (int c = 0; c < 3; ++c) {
                float sg = 1.0f / (1.0f + expf(-v[c]));
                out[(size_t)c * 65536 + n0 + row] = 1.1f * sg - 0.05f;
            }
        }
    }
}

extern "C" void kernel_launch(void* const* d_in, const int* in_sizes, int n_in,
                              void* d_out, int out_size, void* d_ws, size_t ws_size,
                              hipStream_t stream) {
    const float* feature = (const float*)d_in[0];
    const float* cw1 = (const float*)d_in[1];  const float* cb1 = (const float*)d_in[2];
    const float* cw2 = (const float*)d_in[3];  const float* cb2 = (const float*)d_in[4];
    const float* cw3 = (const float*)d_in[5];  const float* cb3 = (const float*)d_in[6];
    const float* cw4 = (const float*)d_in[7];  const float* cb4 = (const float*)d_in[8];
    const float* cw5 = (const float*)d_in[9];  const float* cb5 = (const float*)d_in[10];
    const float* w1  = (const float*)d_in[11]; const float* b1  = (const float*)d_in[12];
    const float* m1_vf = (const float*)d_in[13]; const float* m1_gf = (const float*)d_in[14];
    const float* m1_bf = (const float*)d_in[15];
    const float* m1_vg = (const float*)d_in[16]; const float* m1_gg = (const float*)d_in[17];
    const float* m1_bg = (const float*)d_in[18];
    const float* w2  = (const float*)d_in[19]; const float* b2  = (const float*)d_in[20];
    const float* m2_vf = (const float*)d_in[21]; const float* m2_gf = (const float*)d_in[22];
    const float* m2_bf = (const float*)d_in[23];
    const float* m2_vg = (const float*)d_in[24]; const float* m2_gg = (const float*)d_in[25];
    const float* m2_bg = (const float*)d_in[26];
    const float* w3  = (const float*)d_in[27]; const float* b3  = (const float*)d_in[28];
    float* out = (float*)d_out;

    float* ws = (float*)d_ws;
    size_t off = 0;
    float* sgrid   = ws + off; off += 256 * 32;
    float* cbA     = ws + off; off += 768 * 64;
    float* cbB     = ws + off; off += 768 * 64;
    float* featbuf = ws + off; off += 2048;
    float* c1      = ws + off; off += 1024;
    float* s1f     = ws + off; off += 8 * 512;
    float* s1g     = ws + off; off += 8 * 512;
    float* s2f     = ws + off; off += 8 * 256;
    float* s2g     = ws + off; off += 8 * 256;
    float* Px      = ws + off; off += 256 * 1024;
    float* Py      = ws + off; off += 256 * 1024;
    float* Qx      = ws + off; off += 256 * 512;
    float* Qy      = ws + off; off += 256 * 512;
    unsigned short* m1f_bf = (unsigned short*)(ws + off); off += (size_t)8 * 512 * 512 / 2;
    unsigned short* m1g_bf = (unsigned short*)(ws + off); off += (size_t)8 * 512 * 512 / 2;
    unsigned short* m2f_bf = (unsigned short*)(ws + off); off += (size_t)8 * 256 * 256 / 2;
    unsigned short* m2g_bf = (unsigned short*)(ws + off); off += (size_t)8 * 256 * 256 / 2;
    unsigned short* w2m_bf = (unsigned short*)(ws + off); off += (size_t)512 * 1024 / 2;

    // ---- constants ----
    sgrid_kernel<<<32, 256, 0, stream>>>(sgrid);
    wn_cvt<<<8 * 512, 256, 0, stream>>>(m1_vf, m1_gf, m1f_bf, s1f, 512);
    wn_cvt<<<8 * 512, 256, 0, stream>>>(m1_vg, m1_gg, m1g_bf, s1g, 512);
    wn_cvt<<<8 * 256, 256, 0, stream>>>(m2_vf, m2_gf, m2f_bf, s2f, 256);
    wn_cvt<<<8 * 256, 256, 0, stream>>>(m2_vg, m2_gg, m2g_bf, s2g, 256);
    cvt_w2_kernel<<<(512 * 1024) / 256, 256, 0, stream>>>(w2, w2m_bf);

    // ---- conv trunk ----
    conv_lds<<<768, 256, 0, stream>>>(feature, cw1, cb1, cbA, 448, 192, 8, 1);
    conv_lds<<<768, 256, 0, stream>>>(cbA, cw2, cb2, cbB, 256, 256, 8, 1);
    conv_lds<<<768, 256, 0, stream>>>(cbB, cw3, cb3, cbA, 384, 384, 8, 1);
    conv_lds<<<768, 256, 0, stream>>>(cbA, cw4, cb4, cbB, 256, 256, 8, 0);     // ->6x6
    conv_lds<<<128, 256, 0, stream>>>(cbB, cw5, cb5, featbuf, 768, 128, 6, 0); // ->4x4

    // ---- c1, Px/Py, Qx/Qy ----
    feat_c1_kernel<<<1024 / 4, 256, 0, stream>>>(featbuf, w1, b1, c1);
    pxy_kernel<<<(256 * 1024) / 256, 256, 0, stream>>>(sgrid, w1, c1, Px, Py);
    qxy_kernel<<<(256 * 512) / 256, 256, 0, stream>>>(sgrid, w2, Qx, Qy);

    // ---- fused per-position MLP: 1024 persistent blocks x 64 rows ----
    size_t lds_bytes = (size_t)64 * RS * sizeof(unsigned short);   // 132096
    hipFuncSetAttribute(reinterpret_cast<const void*>(fused_mlp),
                        hipFuncAttributeMaxDynamicSharedMemorySize, (int)lds_bytes);
    fused_mlp<<<1024, 512, lds_bytes, stream>>>(
        Px, Py, Qx, Qy,
        m1f_bf, s1f, m1_bf, m1g_bf, s1g, m1_bg,
        w2m_bf, b2,
        m2f_bf, s2f, m2_bf, m2g_bf, s2g, m2_bg,
        w3, b3, out);
}

// Round 5
// 2268.516 us; speedup vs baseline: 6.3384x; 1.0511x over previous
//
#include <hip/hip_runtime.h>
#include <cmath>

#define LRELU(x) ((x) > 0.0f ? (x) : 0.01f * (x))

typedef __attribute__((ext_vector_type(8))) short short8;
typedef __attribute__((ext_vector_type(4))) float f32x4;
typedef __attribute__((ext_vector_type(2))) unsigned uint2v;

constexpr int RS = 1032;   // LDS master row stride (shorts); row*RS*2 is 8B-aligned

__device__ __forceinline__ unsigned short f2bf(float f) {
    unsigned u = __float_as_uint(f);
    unsigned r = (u + 0x7fff + ((u >> 16) & 1)) >> 16;   // RNE
    return (unsigned short)r;
}
__device__ __forceinline__ float bf2f(unsigned short h) {
    return __uint_as_float((unsigned)h << 16);
}
__device__ __forceinline__ unsigned pk2(unsigned short a, unsigned short b) {
    return (unsigned)a | ((unsigned)b << 16);
}

// ---------------------------------------------------------------------------
// sgrid[t][c] = sin(r_t * 2^((c/2)/2)), r_t=(t-128)*pi/256  (256 x 32)
// ---------------------------------------------------------------------------
__global__ void sgrid_kernel(float* __restrict__ sg) {
    int idx = blockIdx.x * blockDim.x + threadIdx.x;
    if (idx >= 256 * 32) return;
    int t = idx >> 5, c = idx & 31;
    double r = (double)(t - 128) * 3.14159265358979323846 / 256.0;
    double scale = exp2(0.5 * (double)(c >> 1));
    sg[idx] = (float)sin(r * scale);
}

// ---------------------------------------------------------------------------
// Grouped 3x3 conv + lrelu; weights staged coalesced into LDS.
// ---------------------------------------------------------------------------
__global__ __launch_bounds__(256) void conv_lds(
    const float* __restrict__ x, const float* __restrict__ w,
    const float* __restrict__ bias, float* __restrict__ y,
    int Cin_g, int Cout_g, int Hin, int pad) {
    __shared__ float wsh[6912];
    __shared__ float red[256];
    int oc = blockIdx.x;
    int Hout = pad ? Hin : Hin - 2;
    int t = threadIdx.x;
    int nw = Cin_g * 9;
    const float* wb = w + (size_t)oc * nw;
    for (int idx = t; idx < nw; idx += 256) wsh[idx] = wb[idx];
    __syncthreads();
    int p = t & 63, ch = t >> 6;
    int oy = p / Hout, ox = p % Hout;
    int g = oc / Cout_g;
    const float* xb = x + (size_t)g * Cin_g * Hin * Hin;
    bool valid = p < Hout * Hout;
    int S = (Cin_g + 3) >> 2;
    int ic0 = ch * S, ic1 = min(Cin_g, ic0 + S);
    float acc = 0.f;
    if (valid) {
        for (int ic = ic0; ic < ic1; ++ic) {
            const float* xc = xb + (size_t)ic * Hin * Hin;
            const float* wc = wsh + ic * 9;
            #pragma unroll
            for (int ky = 0; ky < 3; ++ky) {
                int iy = oy + ky - pad;
                if (iy < 0 || iy >= Hin) continue;
                #pragma unroll
                for (int kx = 0; kx < 3; ++kx) {
                    int ix = ox + kx - pad;
                    if (ix < 0 || ix >= Hin) continue;
                    acc = fmaf(xc[iy * Hin + ix], wc[ky * 3 + kx], acc);
                }
            }
        }
    }
    red[t] = acc;
    __syncthreads();
    if (t < 64 && valid) {
        float s = red[t] + red[t + 64] + red[t + 128] + red[t + 192] + bias[oc];
        y[(size_t)oc * Hout * Hout + p] = LRELU(s);
    }
}

// ---------------------------------------------------------------------------
// c1[o] = b1[o] + feat . w1[o][32:]
// ---------------------------------------------------------------------------
__global__ void feat_c1_kernel(const float* __restrict__ feat, const float* __restrict__ w1,
                               const float* __restrict__ b1, float* __restrict__ c1) {
    int o = (blockIdx.x * blockDim.x + threadIdx.x) >> 6;
    int lane = threadIdx.x & 63;
    if (o >= 1024) return;
    const float* wr = w1 + (size_t)o * 2080 + 32;
    float sum = 0.f;
    for (int k = lane; k < 2048; k += 64) sum += feat[k] * wr[k];
    #pragma unroll
    for (int off = 32; off; off >>= 1) sum += __shfl_xor(sum, off);
    if (lane == 0) c1[o] = sum + b1[o];
}

// ---------------------------------------------------------------------------
// wn_cvt: bf16 copy of v and s = g/||v|| in one pass (block per row)
// ---------------------------------------------------------------------------
__global__ __launch_bounds__(256) void wn_cvt(const float* __restrict__ v, const float* __restrict__ g,
                                              unsigned short* __restrict__ vbf, float* __restrict__ s,
                                              int K) {
    __shared__ float red[256];
    int r = blockIdx.x, t = threadIdx.x;
    const float* vr = v + (size_t)r * K;
    float sum = 0.f;
    for (int k = t; k < K; k += 256) {
        float x = vr[k];
        sum = fmaf(x, x, sum);
        vbf[(size_t)r * K + k] = f2bf(x);
    }
    red[t] = sum;
    __syncthreads();
    for (int o = 128; o; o >>= 1) {
        if (t < o) red[t] += red[t + o];
        __syncthreads();
    }
    if (t == 0) s[r] = g[r] / sqrtf(red[0]);
}

__global__ void cvt_w2_kernel(const float* __restrict__ w2, unsigned short* __restrict__ dst) {
    int i = blockIdx.x * 256 + threadIdx.x;
    int r = i >> 10, c = i & 1023;
    dst[i] = f2bf(w2[(size_t)r * 1056 + 32 + c]);
}

// ---------------------------------------------------------------------------
// Px/Py, Qx/Qy separable grid tables
// ---------------------------------------------------------------------------
__global__ void pxy_kernel(const float* __restrict__ sg, const float* __restrict__ w1,
                           const float* __restrict__ c1, float* __restrict__ Px,
                           float* __restrict__ Py) {
    int idx = blockIdx.x * 256 + threadIdx.x;  // 256*1024
    int t = idx >> 10, o = idx & 1023;
    const float* wr = w1 + (size_t)o * 2080;
    const float* sr = sg + t * 32;
    float px = 0.f, py = 0.f;
    #pragma unroll
    for (int k = 0; k < 16; ++k) {
        px = fmaf(sr[2 * k], wr[2 * k], px);
        py = fmaf(sr[2 * k + 1], wr[2 * k + 1], py);
    }
    Px[idx] = px + c1[o];
    Py[idx] = py;
}

__global__ void qxy_kernel(const float* __restrict__ sg, const float* __restrict__ w2,
                           float* __restrict__ Qx, float* __restrict__ Qy) {
    int idx = blockIdx.x * 256 + threadIdx.x;  // 256*512
    int t = idx >> 9, o = idx & 511;
    const float* wr = w2 + (size_t)o * 1056;
    const float* sr = sg + t * 32;
    float qx = 0.f, qy = 0.f;
    #pragma unroll
    for (int k = 0; k < 16; ++k) {
        qx = fmaf(sr[2 * k], wr[2 * k], qx);
        qy = fmaf(sr[2 * k + 1], wr[2 * k + 1], qy);
    }
    Qx[idx] = qx;
    Qy[idx] = qy;
}

// ---------------------------------------------------------------------------
// Fused MLP. SWAPPED-OPERAND MFMA: acc = mfma(w_frag, act_frag) puts
// D[row=lane&15][col=quad*4+r] -> each lane owns 4 consecutive cols at a
// fixed row -> b64 LDS epilogue instead of u16 scatter.
// Master hi image (bf16) in LDS [64][RS]; stack-1 lo in VGPRs (packed);
// stack-2 hi cols 0..511 / lo cols 512..1023.
// ---------------------------------------------------------------------------
__device__ __forceinline__ void step1(unsigned short* sm, int w, int l15, int lq,
                                      int srcb, int dstb,
                                      const unsigned short* __restrict__ B,
                                      const float* __restrict__ sc,
                                      const float* __restrict__ bi,
                                      unsigned* lo_half) {
    f32x4 acc[4][4] = {};
    const unsigned short* bbase = B + (size_t)(w * 64 + l15) * 512 + lq * 8;
    const unsigned short* abase = sm + (size_t)l15 * RS + srcb + lq * 8;
    short8 b0[4], b1[4];
    #pragma unroll
    for (int nt = 0; nt < 4; ++nt) b0[nt] = *(const short8*)(bbase + nt * (16 * 512));
    #pragma unroll
    for (int nt = 0; nt < 4; ++nt) b1[nt] = *(const short8*)(bbase + nt * (16 * 512) + 32);
    #pragma unroll
    for (int kc = 0; kc < 16; ++kc) {
        short8 bn[4];
        if (kc < 14) {
            #pragma unroll
            for (int nt = 0; nt < 4; ++nt)
                bn[nt] = *(const short8*)(bbase + nt * (16 * 512) + (kc + 2) * 32);
        }
        short8 af[4];
        #pragma unroll
        for (int mt = 0; mt < 4; ++mt)
            af[mt] = *(const short8*)(abase + (size_t)(mt * 16) * RS + kc * 32);
        #pragma unroll
        for (int mt = 0; mt < 4; ++mt)
            #pragma unroll
            for (int nt = 0; nt < 4; ++nt)
                acc[mt][nt] = __builtin_amdgcn_mfma_f32_16x16x32_bf16(b0[nt], af[mt], acc[mt][nt], 0, 0, 0);
        #pragma unroll
        for (int nt = 0; nt < 4; ++nt) { b0[nt] = b1[nt]; b1[nt] = bn[nt]; }
    }
    #pragma unroll
    for (int nt = 0; nt < 4; ++nt) {
        int nb = w * 64 + nt * 16 + lq * 4;
        float4 s4 = *(const float4*)(sc + nb);
        float4 bb = *(const float4*)(bi + nb);
        #pragma unroll
        for (int mt = 0; mt < 4; ++mt) {
            int row = mt * 16 + l15;
            size_t hidx = (size_t)row * RS + dstb + nb;
            uint2v hold = *(uint2v*)(sm + hidx);
            unsigned* lp = lo_half + (mt * 4 + nt) * 2;
            float v0 = LRELU(acc[mt][nt][0] * s4.x + bb.x);
            float v1 = LRELU(acc[mt][nt][1] * s4.y + bb.y);
            float v2 = LRELU(acc[mt][nt][2] * s4.z + bb.z);
            float v3 = LRELU(acc[mt][nt][3] * s4.w + bb.w);
            v0 += bf2f((unsigned short)(hold[0] & 0xffffu)) + bf2f((unsigned short)(lp[0] & 0xffffu));
            v1 += bf2f((unsigned short)(hold[0] >> 16)) + bf2f((unsigned short)(lp[0] >> 16));
            v2 += bf2f((unsigned short)(hold[1] & 0xffffu)) + bf2f((unsigned short)(lp[1] & 0xffffu));
            v3 += bf2f((unsigned short)(hold[1] >> 16)) + bf2f((unsigned short)(lp[1] >> 16));
            unsigned short h0 = f2bf(v0), h1 = f2bf(v1), h2 = f2bf(v2), h3 = f2bf(v3);
            uint2v hnew; hnew[0] = pk2(h0, h1); hnew[1] = pk2(h2, h3);
            *(uint2v*)(sm + hidx) = hnew;
            lp[0] = pk2(f2bf(v0 - bf2f(h0)), f2bf(v1 - bf2f(h1)));
            lp[1] = pk2(f2bf(v2 - bf2f(h2)), f2bf(v3 - bf2f(h3)));
        }
    }
}

__device__ __forceinline__ void step2(unsigned short* sm, int w, int l15, int lq,
                                      int srcb, int dstb,
                                      const unsigned short* __restrict__ B,
                                      const float* __restrict__ sc,
                                      const float* __restrict__ bi) {
    f32x4 acc[4][2] = {};
    const unsigned short* bbase = B + (size_t)(w * 32 + l15) * 256 + lq * 8;
    const unsigned short* abase = sm + (size_t)l15 * RS + srcb + lq * 8;
    short8 b0[2], b1[2];
    #pragma unroll
    for (int nt = 0; nt < 2; ++nt) b0[nt] = *(const short8*)(bbase + nt * (16 * 256));
    #pragma unroll
    for (int nt = 0; nt < 2; ++nt) b1[nt] = *(const short8*)(bbase + nt * (16 * 256) + 32);
    #pragma unroll
    for (int kc = 0; kc < 8; ++kc) {
        short8 bn[2];
        if (kc < 6) {
            #pragma unroll
            for (int nt = 0; nt < 2; ++nt)
                bn[nt] = *(const short8*)(bbase + nt * (16 * 256) + (kc + 2) * 32);
        }
        short8 af[4];
        #pragma unroll
        for (int mt = 0; mt < 4; ++mt)
            af[mt] = *(const short8*)(abase + (size_t)(mt * 16) * RS + kc * 32);
        #pragma unroll
        for (int mt = 0; mt < 4; ++mt)
            #pragma unroll
            for (int nt = 0; nt < 2; ++nt)
                acc[mt][nt] = __builtin_amdgcn_mfma_f32_16x16x32_bf16(b0[nt], af[mt], acc[mt][nt], 0, 0, 0);
        #pragma unroll
        for (int nt = 0; nt < 2; ++nt) { b0[nt] = b1[nt]; b1[nt] = bn[nt]; }
    }
    #pragma unroll
    for (int nt = 0; nt < 2; ++nt) {
        int nb = w * 32 + nt * 16 + lq * 4;
        float4 s4 = *(const float4*)(sc + nb);
        float4 bb = *(const float4*)(bi + nb);
        #pragma unroll
        for (int mt = 0; mt < 4; ++mt) {
            int row = mt * 16 + l15;
            size_t hidx = (size_t)row * RS + dstb + nb;
            uint2v hold = *(uint2v*)(sm + hidx);
            uint2v lold = *(uint2v*)(sm + hidx + 512);
            float v0 = LRELU(acc[mt][nt][0] * s4.x + bb.x);
            float v1 = LRELU(acc[mt][nt][1] * s4.y + bb.y);
            float v2 = LRELU(acc[mt][nt][2] * s4.z + bb.z);
            float v3 = LRELU(acc[mt][nt][3] * s4.w + bb.w);
            v0 += bf2f((unsigned short)(hold[0] & 0xffffu)) + bf2f((unsigned short)(lold[0] & 0xffffu));
            v1 += bf2f((unsigned short)(hold[0] >> 16)) + bf2f((unsigned short)(lold[0] >> 16));
            v2 += bf2f((unsigned short)(hold[1] & 0xffffu)) + bf2f((unsigned short)(lold[1] & 0xffffu));
            v3 += bf2f((unsigned short)(hold[1] >> 16)) + bf2f((unsigned short)(lold[1] >> 16));
            unsigned short h0 = f2bf(v0), h1 = f2bf(v1), h2 = f2bf(v2), h3 = f2bf(v3);
            uint2v hnew; hnew[0] = pk2(h0, h1); hnew[1] = pk2(h2, h3);
            uint2v lnew; lnew[0] = pk2(f2bf(v0 - bf2f(h0)), f2bf(v1 - bf2f(h1)));
            lnew[1] = pk2(f2bf(v2 - bf2f(h2)), f2bf(v3 - bf2f(h3)));
            *(uint2v*)(sm + hidx) = hnew;
            *(uint2v*)(sm + hidx + 512) = lnew;
        }
    }
}

__global__ __launch_bounds__(512, 2) void fused_mlp(
    const float* __restrict__ Px, const float* __restrict__ Py,
    const float* __restrict__ Qx, const float* __restrict__ Qy,
    const unsigned short* __restrict__ m1f, const float* __restrict__ s1f, const float* __restrict__ bf1,
    const unsigned short* __restrict__ m1g, const float* __restrict__ s1g, const float* __restrict__ bg1,
    const unsigned short* __restrict__ w2m, const float* __restrict__ b2,
    const unsigned short* __restrict__ m2f, const float* __restrict__ s2f, const float* __restrict__ bf2_,
    const unsigned short* __restrict__ m2g, const float* __restrict__ s2g, const float* __restrict__ bg2_,
    const float* __restrict__ w3, const float* __restrict__ b3,
    float* __restrict__ out) {
    extern __shared__ unsigned short sm[];     // [64][RS]
    int tid = threadIdx.x;
    int w = tid >> 6, l = tid & 63;
    int l15 = l & 15, lq = l >> 4;
    int n0 = blockIdx.x * 64;
    int i = n0 >> 8, jb = n0 & 255;

    unsigned lo_pk[64];   // stack-1 lo plane, col-quad packed: [half][mt][nt][pair]

    // ---- P1: mid init; hi -> LDS (b64), lo -> VGPR ----
    #pragma unroll
    for (int h = 0; h < 2; ++h) {
        #pragma unroll
        for (int nt = 0; nt < 4; ++nt) {
            int nb = h * 512 + w * 64 + nt * 16 + lq * 4;
            float4 px4 = *(const float4*)(Px + (size_t)i * 1024 + nb);
            #pragma unroll
            for (int mt = 0; mt < 4; ++mt) {
                int row = mt * 16 + l15;
                float4 py4 = *(const float4*)(Py + (size_t)(jb + row) * 1024 + nb);
                float v0 = LRELU(px4.x + py4.x);
                float v1 = LRELU(px4.y + py4.y);
                float v2 = LRELU(px4.z + py4.z);
                float v3 = LRELU(px4.w + py4.w);
                unsigned short h0 = f2bf(v0), h1 = f2bf(v1), h2 = f2bf(v2), h3 = f2bf(v3);
                uint2v hv; hv[0] = pk2(h0, h1); hv[1] = pk2(h2, h3);
                *(uint2v*)(sm + (size_t)row * RS + nb) = hv;
                unsigned* lp = lo_pk + h * 32 + (mt * 4 + nt) * 2;
                lp[0] = pk2(f2bf(v0 - bf2f(h0)), f2bf(v1 - bf2f(h1)));
                lp[1] = pk2(f2bf(v2 - bf2f(h2)), f2bf(v3 - bf2f(h3)));
            }
        }
    }
    __syncthreads();

    // ---- P2: stack 1 ----
    for (int t = 0; t < 8; ++t) {
        step1(sm, w, l15, lq, 512, 0, m1f + (size_t)t * 512 * 512, s1f + t * 512, bf1 + t * 512, lo_pk);
        __syncthreads();
        step1(sm, w, l15, lq, 0, 512, m1g + (size_t)t * 512 * 512, s1g + t * 512, bg1 + t * 512, lo_pk + 32);
        __syncthreads();
    }

    // ---- P3: h2 = lrelu(Qx+Qy + mid @ w2m^T + b2); overwrite master ----
    {
        f32x4 acc[4][4] = {};
        const unsigned short* bbase = w2m + (size_t)(w * 64 + l15) * 1024 + lq * 8;
        const unsigned short* abase = sm + (size_t)l15 * RS + lq * 8;
        short8 b0[4], b1[4];
        #pragma unroll
        for (int nt = 0; nt < 4; ++nt) b0[nt] = *(const short8*)(bbase + nt * (16 * 1024));
        #pragma unroll
        for (int nt = 0; nt < 4; ++nt) b1[nt] = *(const short8*)(bbase + nt * (16 * 1024) + 32);
        #pragma unroll
        for (int kc = 0; kc < 32; ++kc) {
            short8 bn[4];
            if (kc < 30) {
                #pragma unroll
                for (int nt = 0; nt < 4; ++nt)
                    bn[nt] = *(const short8*)(bbase + nt * (16 * 1024) + (kc + 2) * 32);
            }
            short8 af[4];
            #pragma unroll
            for (int mt = 0; mt < 4; ++mt)
                af[mt] = *(const short8*)(abase + (size_t)(mt * 16) * RS + kc * 32);
            #pragma unroll
            for (int mt = 0; mt < 4; ++mt)
                #pragma unroll
                for (int nt = 0; nt < 4; ++nt)
                    acc[mt][nt] = __builtin_amdgcn_mfma_f32_16x16x32_bf16(b0[nt], af[mt], acc[mt][nt], 0, 0, 0);
            #pragma unroll
            for (int nt = 0; nt < 4; ++nt) { b0[nt] = b1[nt]; b1[nt] = bn[nt]; }
        }
        __syncthreads();   // all A reads of mid done before overwrite
        #pragma unroll
        for (int nt = 0; nt < 4; ++nt) {
            int nb = w * 64 + nt * 16 + lq * 4;      // 0..511
            float4 qx4 = *(const float4*)(Qx + (size_t)i * 512 + nb);
            float4 b24 = *(const float4*)(b2 + nb);
            #pragma unroll
            for (int mt = 0; mt < 4; ++mt) {
                int row = mt * 16 + l15;
                float4 qy4 = *(const float4*)(Qy + (size_t)(jb + row) * 512 + nb);
                float v0 = LRELU(acc[mt][nt][0] + qx4.x + qy4.x + b24.x);
                float v1 = LRELU(acc[mt][nt][1] + qx4.y + qy4.y + b24.y);
                float v2 = LRELU(acc[mt][nt][2] + qx4.z + qy4.z + b24.z);
                float v3 = LRELU(acc[mt][nt][3] + qx4.w + qy4.w + b24.w);
                unsigned short h0 = f2bf(v0), h1 = f2bf(v1), h2 = f2bf(v2), h3 = f2bf(v3);
                size_t hidx = (size_t)row * RS + nb;
                uint2v hv; hv[0] = pk2(h0, h1); hv[1] = pk2(h2, h3);
                uint2v lv; lv[0] = pk2(f2bf(v0 - bf2f(h0)), f2bf(v1 - bf2f(h1)));
                lv[1] = pk2(f2bf(v2 - bf2f(h2)), f2bf(v3 - bf2f(h3)));
                *(uint2v*)(sm + hidx) = hv;
                *(uint2v*)(sm + hidx + 512) = lv;
            }
        }
    }
    __syncthreads();

    // ---- P4: stack 2 ----
    for (int t = 0; t < 8; ++t) {
        step2(sm, w, l15, lq, 256, 0, m2f + (size_t)t * 256 * 256, s2f + t * 256, bf2_ + t * 256);
        __syncthreads();
        step2(sm, w, l15, lq, 0, 256, m2g + (size_t)t * 256 * 256, s2g + t * 256, bg2_ + t * 256);
        __syncthreads();
    }

    // ---- P5: rgb ----
    #pragma unroll
    for (int rr = 0; rr < 8; ++rr) {
        int row = w * 8 + rr;
        float s0 = 0.f, s1 = 0.f, s2 = 0.f;
        #pragma unroll
        for (int it = 0; it < 8; ++it) {
            int k = it * 64 + l;
            size_t hidx = (size_t)row * RS + k;
            float hv = bf2f(sm[hidx]) + bf2f(sm[hidx + 512]);
            s0 = fmaf(hv, w3[k], s0);
            s1 = fmaf(hv, w3[512 + k], s1);
            s2 = fmaf(hv, w3[1024 + k], s2);
        }
        #pragma unroll
        for (int off = 32; off; off >>= 1) {
            s0 += __shfl_xor(s0, off);
            s1 += __shfl_xor(s1, off);
            s2 += __shfl_xor(s2, off);
        }
        if (l == 0) {
            float v[3] = {s0 + b3[0], s1 + b3[1], s2 + b3[2]};
            #pragma unroll
            for (int c = 0; c < 3; ++c) {
                float sg = 1.0f / (1.0f + expf(-v[c]));
                out[(size_t)c * 65536 + n0 + row] = 1.1f * sg - 0.05f;
            }
        }
    }
}

extern "C" void kernel_launch(void* const* d_in, const int* in_sizes, int n_in,
                              void* d_out, int out_size, void* d_ws, size_t ws_size,
                              hipStream_t stream) {
    const float* feature = (const float*)d_in[0];
    const float* cw1 = (const float*)d_in[1];  const float* cb1 = (const float*)d_in[2];
    const float* cw2 = (const float*)d_in[3];  const float* cb2 = (const float*)d_in[4];
    const float* cw3 = (const float*)d_in[5];  const float* cb3 = (const float*)d_in[6];
    const float* cw4 = (const float*)d_in[7];  const float* cb4 = (const float*)d_in[8];
    const float* cw5 = (const float*)d_in[9];  const float* cb5 = (const float*)d_in[10];
    const float* w1  = (const float*)d_in[11]; const float* b1  = (const float*)d_in[12];
    const float* m1_vf = (const float*)d_in[13]; const float* m1_gf = (const float*)d_in[14];
    const float* m1_bf = (const float*)d_in[15];
    const float* m1_vg = (const float*)d_in[16]; const float* m1_gg = (const float*)d_in[17];
    const float* m1_bg = (const float*)d_in[18];
    const float* w2  = (const float*)d_in[19]; const float* b2  = (const float*)d_in[20];
    const float* m2_vf = (const float*)d_in[21]; const float* m2_gf = (const float*)d_in[22];
    const float* m2_bf = (const float*)d_in[23];
    const float* m2_vg = (const float*)d_in[24]; const float* m2_gg = (const float*)d_in[25];
    const float* m2_bg = (const float*)d_in[26];
    const float* w3  = (const float*)d_in[27]; const float* b3  = (const float*)d_in[28];
    float* out = (float*)d_out;

    float* ws = (float*)d_ws;
    size_t off = 0;
    float* sgrid   = ws + off; off += 256 * 32;
    float* cbA     = ws + off; off += 768 * 64;
    float* cbB     = ws + off; off += 768 * 64;
    float* featbuf = ws + off; off += 2048;
    float* c1      = ws + off; off += 1024;
    float* s1f     = ws + off; off += 8 * 512;
    float* s1g     = ws + off; off += 8 * 512;
    float* s2f     = ws + off; off += 8 * 256;
    float* s2g     = ws + off; off += 8 * 256;
    float* Px      = ws + off; off += 256 * 1024;
    float* Py      = ws + off; off += 256 * 1024;
    float* Qx      = ws + off; off += 256 * 512;
    float* Qy      = ws + off; off += 256 * 512;
    unsigned short* m1f_bf = (unsigned short*)(ws + off); off += (size_t)8 * 512 * 512 / 2;
    unsigned short* m1g_bf = (unsigned short*)(ws + off); off += (size_t)8 * 512 * 512 / 2;
    unsigned short* m2f_bf = (unsigned short*)(ws + off); off += (size_t)8 * 256 * 256 / 2;
    unsigned short* m2g_bf = (unsigned short*)(ws + off); off += (size_t)8 * 256 * 256 / 2;
    unsigned short* w2m_bf = (unsigned short*)(ws + off); off += (size_t)512 * 1024 / 2;

    // ---- constants ----
    sgrid_kernel<<<32, 256, 0, stream>>>(sgrid);
    wn_cvt<<<8 * 512, 256, 0, stream>>>(m1_vf, m1_gf, m1f_bf, s1f, 512);
    wn_cvt<<<8 * 512, 256, 0, stream>>>(m1_vg, m1_gg, m1g_bf, s1g, 512);
    wn_cvt<<<8 * 256, 256, 0, stream>>>(m2_vf, m2_gf, m2f_bf, s2f, 256);
    wn_cvt<<<8 * 256, 256, 0, stream>>>(m2_vg, m2_gg, m2g_bf, s2g, 256);
    cvt_w2_kernel<<<(512 * 1024) / 256, 256, 0, stream>>>(w2, w2m_bf);

    // ---- conv trunk ----
    conv_lds<<<768, 256, 0, stream>>>(feature, cw1, cb1, cbA, 448, 192, 8, 1);
    conv_lds<<<768, 256, 0, stream>>>(cbA, cw2, cb2, cbB, 256, 256, 8, 1);
    conv_lds<<<768, 256, 0, stream>>>(cbB, cw3, cb3, cbA, 384, 384, 8, 1);
    conv_lds<<<768, 256, 0, stream>>>(cbA, cw4, cb4, cbB, 256, 256, 8, 0);     // ->6x6
    conv_lds<<<128, 256, 0, stream>>>(cbB, cw5, cb5, featbuf, 768, 128, 6, 0); // ->4x4

    // ---- c1, Px/Py, Qx/Qy ----
    feat_c1_kernel<<<1024 / 4, 256, 0, stream>>>(featbuf, w1, b1, c1);
    pxy_kernel<<<(256 * 1024) / 256, 256, 0, stream>>>(sgrid, w1, c1, Px, Py);
    qxy_kernel<<<(256 * 512) / 256, 256, 0, stream>>>(sgrid, w2, Qx, Qy);

    // ---- fused per-position MLP: 1024 blocks x 64 rows ----
    size_t lds_bytes = (size_t)64 * RS * sizeof(unsigned short);   // 132096
    hipFuncSetAttribute(reinterpret_cast<const void*>(fused_mlp),
                        hipFuncAttributeMaxDynamicSharedMemorySize, (int)lds_bytes);
    fused_mlp<<<1024, 512, lds_bytes, stream>>>(
        Px, Py, Qx, Qy,
        m1f_bf, s1f, m1_bf, m1g_bf, s1g, m1_bg,
        w2m_bf, b2,
        m2f_bf, s2f, m2_bf, m2g_bf, s2g, m2_bg,
        w3, b3, out);
}